// Round 3
// baseline (442.770 us; speedup 1.0000x reference)
//
#include <hip/hip_runtime.h>
#include <hip/hip_bf16.h>

#define NH 128   // hidden
#define NC 384   // edge feature dim
#define NK 32    // neighbors

typedef __attribute__((ext_vector_type(8))) short short8v;   // 8 bf16
typedef __attribute__((ext_vector_type(4))) float f32x4;

#define MFMA16(a, b, c) __builtin_amdgcn_mfma_f32_16x16x32_bf16((a), (b), (c), 0, 0, 0)

__device__ __forceinline__ ushort f2bf(float x) {
  __hip_bfloat16 h = __float2bfloat16(x);   // compiler emits v_cvt_pk_bf16_f32 pairs
  ushort u;
  __builtin_memcpy(&u, &h, 2);
  return u;
}

__device__ __forceinline__ short8v ld8(const ushort* p) {
  return *reinterpret_cast<const short8v*>(p);
}
__device__ __forceinline__ void st8(ushort* p, short8v v) {
  *reinterpret_cast<short8v*>(p) = v;
}

__device__ __forceinline__ short8v pack8(float4 a, float4 b) {
  short8v v;
  v[0] = (short)f2bf(a.x); v[1] = (short)f2bf(a.y);
  v[2] = (short)f2bf(a.z); v[3] = (short)f2bf(a.w);
  v[4] = (short)f2bf(b.x); v[5] = (short)f2bf(b.y);
  v[6] = (short)f2bf(b.z); v[7] = (short)f2bf(b.w);
  return v;
}

// gelu(x) = x * sigmoid(x*(1.5958 + 0.07136 x^2)); |err| vs erf-GELU < 1e-3
__device__ __forceinline__ float gelu_f(float x) {
  float x2 = x * x;
  float m = __builtin_fmaf(0.07135481283f, x2, 1.595769122f);
  float e = __expf(-x * m);
  return x * __builtin_amdgcn_rcpf(1.0f + e);
}

// ---------------------------------------------------------------------------
// Weight packing: src row-major [k][col] f32 -> bf16 [k/8][col][k%8]
// ushort offsets: W1p 0 (64Ki), W2p 65536 (16Ki), W3p 81920 (16Ki),
// Winp 98304 (64Ki), Woutp 163840 (64Ki). Total 448 KB.
// ---------------------------------------------------------------------------
__global__ __launch_bounds__(256) void pack_w(
    const float* __restrict__ W1, const float* __restrict__ W2,
    const float* __restrict__ W3, const float* __restrict__ Win,
    const float* __restrict__ Wout, ushort* __restrict__ ws) {
  int id = blockIdx.x * 256 + threadIdx.x;
  if (id < 65536) {                       // W1: K=512, ncol=128
    int t = id, k = t >> 7, c = t & 127;
    ws[(((k >> 3) << 7) + c) * 8 + (k & 7)] = f2bf(W1[t]);
  } else if (id < 81920) {                // W2
    int t = id - 65536, k = t >> 7, c = t & 127;
    ws[65536 + (((k >> 3) << 7) + c) * 8 + (k & 7)] = f2bf(W2[t]);
  } else if (id < 98304) {                // W3
    int t = id - 81920, k = t >> 7, c = t & 127;
    ws[81920 + (((k >> 3) << 7) + c) * 8 + (k & 7)] = f2bf(W3[t]);
  } else if (id < 163840) {               // Win: K=128, ncol=512
    int t = id - 98304, k = t >> 9, c = t & 511;
    ws[98304 + (((k >> 3) << 9) + c) * 8 + (k & 7)] = f2bf(Win[t]);
  } else {                                // Wout: K=512, ncol=128
    int t = id - 163840, k = t >> 7, c = t & 127;
    ws[163840 + (((k >> 3) << 7) + c) * 8 + (k & 7)] = f2bf(Wout[t]);
  }
}

// ---------------------------------------------------------------------------
// Persistent fused kernel: 512 blocks x 512 threads, each block loops over
// node-pairs (stride gridDim.x). h_E of iter t+1 prefetched (reg-staged)
// during iter t compute; chunk j of iter t lives in LDS buffer (t+j)&1;
// H1/H2 time-share the same two 16KB buffers. FFN fused at block end over
// the block's own <=20 h_mid rows (kept in LDS).
// ---------------------------------------------------------------------------
__global__ __launch_bounds__(512, 4) void msg_ffn(
    const float* __restrict__ hV, const float* __restrict__ hE,
    const float* __restrict__ maskV, const float* __restrict__ mAtt,
    const ushort* __restrict__ wsu,
    const float* __restrict__ b1, const float* __restrict__ b2,
    const float* __restrict__ b3, const float* __restrict__ g1,
    const float* __restrict__ be1, const float* __restrict__ binf,
    const float* __restrict__ bout, const float* __restrict__ g2,
    const float* __restrict__ be2, float* __restrict__ out, int N) {
  const ushort* W1p = wsu;
  const ushort* W2p = wsu + 65536;
  const ushort* W3p = wsu + 81920;
  const ushort* Winp = wsu + 98304;
  const ushort* Woutp = wsu + 163840;

  __shared__ ushort sEb[2][8192];      // 2 x 16KB rotating chunk/H buffers
  __shared__ float  sHmidF[20 * 132];  // block's h_mid rows (f32, stride 132)
  __shared__ ushort sHV[2][256];       // hV bf16, double-buffered (2 nodes)
  __shared__ float  sHVf[2][256];      // hV f32 for LN1 residual
  __shared__ float  sMA[2][64];        // mask_attend, double-buffered
  __shared__ float  sDh[256];          // edge-sum result (2 nodes x 128)
  __shared__ float  sRed[16];

  const int tid = threadIdx.x;
  const int w = tid >> 6, lane = tid & 63;
  const int g = lane >> 4, lr = lane & 15;
  const int colbase = (w << 4) + lr;

  const int pairsTotal = (N + 1) >> 1;
  const int bId = blockIdx.x;
  const int stride = gridDim.x;
  const int T = (bId < pairsTotal) ? ((pairsTotal - bId + stride - 1) / stride) : 0;

  // staging geometry: 64 rows x 8 threads, 16B chunks
  const int srow = tid >> 3, scb = tid & 7;
  const int snode = srow >> 5, sedge = srow & 31;
  const int rsw = srow & 15;

  float4 Lb0[2][2], Lb1[2][2], Lc2[2][2];
  float4 hvreg = (float4){0.f, 0.f, 0.f, 0.f};
  float  mareg = 0.f;
  bool   zhold = true;

  auto hEbase = [&](int p) -> const float* {
    int n = 2 * p + snode;
    int nc = n < N ? n : 0;
    return hE + ((size_t)nc * NK + sedge) * NC + scb * 8;
  };
  auto loadCh = [&](const float* bp, int q, float4 L[2][2]) {
    const float4* p0 = reinterpret_cast<const float4*>(bp + q * 128);
    const float4* p1 = reinterpret_cast<const float4*>(bp + q * 128 + 64);
    L[0][0] = p0[0]; L[0][1] = p0[1];
    L[1][0] = p1[0]; L[1][1] = p1[1];
  };
  auto writeCh = [&](ushort* buf, float4 L[2][2], bool zz) {
#pragma unroll
    for (int h = 0; h < 2; ++h) {
      short8v v = zz ? (short8v){0, 0, 0, 0, 0, 0, 0, 0} : pack8(L[h][0], L[h][1]);
      st8(buf + srow * 128 + (((scb + 8 * h) ^ rsw) << 3), v);
    }
  };
  auto loadHVMA = [&](int p) {
    if (tid < 64) {
      int nd = tid >> 5, c4 = tid & 31;
      int n = 2 * p + nd;
      int nc = n < N ? n : 0;
      hvreg = *reinterpret_cast<const float4*>(hV + (size_t)nc * NH + c4 * 4);
      if (n >= N) hvreg = (float4){0.f, 0.f, 0.f, 0.f};
      mareg = (n < N) ? mAtt[(size_t)(2 * p) * NK + tid] : 0.f;
    }
  };
  auto storeHVMA = [&](int par) {
    if (tid < 64) {
      int nd = tid >> 5, c4 = tid & 31;
      *reinterpret_cast<float4*>(&sHVf[par][nd * 128 + c4 * 4]) = hvreg;
      ushort4 hb;
      hb.x = f2bf(hvreg.x); hb.y = f2bf(hvreg.y);
      hb.z = f2bf(hvreg.z); hb.w = f2bf(hvreg.w);
      *reinterpret_cast<ushort4*>(&sHV[par][nd * 128 + c4 * 4]) = hb;
      sMA[par][tid] = mareg;
    }
  };
  auto mfmaChunk = [&](const ushort* buf, int ktBase, f32x4 acc[4]) {
#pragma unroll
    for (int j = 0; j < 4; ++j) {
      short8v bfr = ld8(W1p + (((ktBase + j) * 4 + g) * 128 + colbase) * 8);
      const int kcg = j * 4 + g;
#pragma unroll
      for (int rt = 0; rt < 4; ++rt) {
        const int row = rt * 16 + lr;
        short8v a = ld8(buf + row * 128 + ((kcg ^ (row & 15)) << 3));
        acc[rt] = MFMA16(a, bfr, acc[rt]);
      }
    }
  };
  auto mfma128 = [&](const ushort* Wp, const ushort* buf, f32x4 acc[4]) {
#pragma unroll
    for (int kt = 0; kt < 4; ++kt) {
      short8v bfr = ld8(Wp + ((kt * 4 + g) * 128 + colbase) * 8);
      const int kcg = kt * 4 + g;
#pragma unroll
      for (int rt = 0; rt < 4; ++rt) {
        const int row = rt * 16 + lr;
        short8v a = ld8(buf + row * 128 + ((kcg ^ (row & 15)) << 3));
        acc[rt] = MFMA16(a, bfr, acc[rt]);
      }
    }
  };
  auto epiStore = [&](ushort* buf, f32x4 acc[4], const float* bias) {
    const float bs = bias[colbase];
#pragma unroll
    for (int rt = 0; rt < 4; ++rt)
#pragma unroll
      for (int i = 0; i < 4; ++i) {
        const int rr = rt * 16 + g * 4 + i;
        buf[rr * 128 + ((((colbase >> 3) ^ (rr & 15)) << 3) | (colbase & 7))] =
            f2bf(gelu_f(acc[rt][i] + bs));
      }
  };

  // -------- prologue: fill iter-0 state --------
  if (T > 0) {
    const float* bp = hEbase(bId);
    const bool z0 = (2 * bId + snode) >= N;
    loadCh(bp, 0, Lb0);
    loadCh(bp, 1, Lb1);
    loadCh(bp, 2, Lc2);
    loadHVMA(bId);
    writeCh(sEb[0], Lb0, z0);
    writeCh(sEb[1], Lb1, z0);
    zhold = z0;
    storeHVMA(0);
    __syncthreads();
  }

  // -------- main persistent loop --------
  for (int t = 0; t < T; ++t) {
    const int par = t & 1, nxt = par ^ 1;
    ushort* bufX = sEb[par];
    ushort* bufY = sEb[nxt];

    // issue prefetch for pair t+1 (chunks 0,1 + hv/mask)
    const int pn = bId + (t + 1) * stride;
    const int pc = pn < pairsTotal ? pn : 0;
    const bool zb = (2 * pc + snode) >= N;
    const float* bp = hEbase(pc);
    loadCh(bp, 0, Lb0);
    loadCh(bp, 1, Lb1);
    loadHVMA(pc);

    // ===== layer 1 =====
    f32x4 acc[4];
#pragma unroll
    for (int rt = 0; rt < 4; ++rt) acc[rt] = (f32x4){0.f, 0.f, 0.f, 0.f};
    // p0: hV part (kt 0..3) + chunk0 from bufX
#pragma unroll
    for (int kt = 0; kt < 4; ++kt) {
      short8v bfr = ld8(W1p + ((kt * 4 + g) * 128 + colbase) * 8);
      short8v a0 = ld8(&sHV[par][kt * 32 + g * 8]);
      short8v a1 = ld8(&sHV[par][128 + kt * 32 + g * 8]);
      acc[0] = MFMA16(a0, bfr, acc[0]);
      acc[1] = MFMA16(a0, bfr, acc[1]);
      acc[2] = MFMA16(a1, bfr, acc[2]);
      acc[3] = MFMA16(a1, bfr, acc[3]);
    }
    mfmaChunk(bufX, 4, acc);
    __syncthreads();
    // write this iter's chunk2 (held from last iter's batch) -> bufX
    writeCh(bufX, Lc2, zhold);
    // issue chunk2 of pair t+1 into the freed regs
    loadCh(bp, 2, Lc2);
    zhold = zb;
    // p1: chunk1 from bufY
    mfmaChunk(bufY, 8, acc);
    __syncthreads();
    // p2: chunk2 from bufX
    mfmaChunk(bufX, 12, acc);
    __syncthreads();
    // layer1 epilogue -> H1 into bufY (c1 dead after p1)
    epiStore(bufY, acc, b1);
    __syncthreads();

    // ===== layer 2: bufY(H1) -> bufX(H2) =====
    f32x4 acc2[4];
#pragma unroll
    for (int rt = 0; rt < 4; ++rt) acc2[rt] = (f32x4){0.f, 0.f, 0.f, 0.f};
    mfma128(W2p, bufY, acc2);
    epiStore(bufX, acc2, b2);
    __syncthreads();

    // ===== layer 3: bufX(H2); also write next c0 -> bufY =====
    f32x4 acc3[4];
#pragma unroll
    for (int rt = 0; rt < 4; ++rt) acc3[rt] = (f32x4){0.f, 0.f, 0.f, 0.f};
    mfma128(W3p, bufX, acc3);
    writeCh(bufY, Lb0, zb);
    {
      const float bias = b3[colbase];
      float ns0 = 0.f, ns1 = 0.f;
#pragma unroll
      for (int rt = 0; rt < 4; ++rt) {
        float s = 0.f;
#pragma unroll
        for (int i = 0; i < 4; ++i) {
          const int e2 = (rt & 1) * 16 + g * 4 + i;
          const int nd = rt >> 1;
          s += (acc3[rt][i] + bias) * sMA[par][nd * 32 + e2];
        }
        s += __shfl_xor(s, 16, 64);
        s += __shfl_xor(s, 32, 64);
        if (rt < 2) ns0 += s; else ns1 += s;
      }
      if (g == 0) { sDh[colbase] = ns0; sDh[128 + colbase] = ns1; }
    }
    __syncthreads();

    // ===== LN1 -> sHmidF rows 2t,2t+1; write next c1 -> bufX; stage next hv/ma
    float x_ln = 0.f;
    if (tid < 256) {
      const int nd = tid >> 7, i = tid & 127;
      x_ln = sHVf[par][nd * 128 + i] + sDh[nd * 128 + i] * (1.f / 30.f);
      float s = x_ln, qv = x_ln * x_ln;
#pragma unroll
      for (int d = 1; d < 64; d <<= 1) {
        s += __shfl_xor(s, d, 64);
        qv += __shfl_xor(qv, d, 64);
      }
      if (lane == 0) { sRed[w * 2] = s; sRed[w * 2 + 1] = qv; }
    }
    writeCh(bufX, Lb1, zb);
    storeHVMA(nxt);
    __syncthreads();
    if (tid < 256) {
      const int nd = tid >> 7, i = tid & 127;
      const int wb = nd * 2;
      const float s = sRed[wb * 2] + sRed[wb * 2 + 2];
      const float qv = sRed[wb * 2 + 1] + sRed[wb * 2 + 3];
      const float mean = s * (1.f / 128.f);
      const float var = qv * (1.f / 128.f) - mean * mean;
      const float y = (x_ln - mean) * rsqrtf(var + 1e-5f) * g1[i] + be1[i];
      sHmidF[(2 * t + nd) * 132 + i] = y;
    }
    __syncthreads();
  }

  // ================= fused FFN over this block's R rows =================
  if (T > 0) {
    const int R = 2 * T;                    // <= 20
    ushort* sHf = &sEb[0][0];               // [row][512] bf16, swizzled (20KB)
    float*  sYF = reinterpret_cast<float*>(
        reinterpret_cast<char*>(&sEb[0][0]) + 20480);  // [20][132] f32

    // ---- layer in: [R,128] @ Win -> gelu -> sHf ----
    f32x4 accI[4][2];
#pragma unroll
    for (int ct = 0; ct < 4; ++ct)
#pragma unroll
      for (int rt = 0; rt < 2; ++rt) accI[ct][rt] = (f32x4){0.f, 0.f, 0.f, 0.f};
#pragma unroll
    for (int kt = 0; kt < 4; ++kt) {
      short8v afr[2];
#pragma unroll
      for (int rt = 0; rt < 2; ++rt) {
        const int row = rt * 16 + lr;
        if (row < R) {
          const float4* ap =
              reinterpret_cast<const float4*>(&sHmidF[row * 132 + kt * 32 + g * 8]);
          afr[rt] = pack8(ap[0], ap[1]);
        } else {
          afr[rt] = (short8v){0, 0, 0, 0, 0, 0, 0, 0};
        }
      }
#pragma unroll
      for (int ct = 0; ct < 4; ++ct) {
        const int col = (w << 6) + ct * 16 + lr;
        short8v bfr = ld8(Winp + ((kt * 4 + g) * 512 + col) * 8);
        accI[ct][0] = MFMA16(afr[0], bfr, accI[ct][0]);
        accI[ct][1] = MFMA16(afr[1], bfr, accI[ct][1]);
      }
    }
    __syncthreads();   // sEb chunk reads fully done before overwrite as sHf
#pragma unroll
    for (int ct = 0; ct < 4; ++ct) {
      const int col = (w << 6) + ct * 16 + lr;
      const float bi = binf[col];
      const int c8 = col >> 3;
#pragma unroll
      for (int rt = 0; rt < 2; ++rt)
#pragma unroll
        for (int i = 0; i < 4; ++i) {
          const int row = rt * 16 + g * 4 + i;
          if (row < R)
            sHf[row * 512 + (((c8 & 48) | ((c8 ^ row) & 15)) << 3) + (col & 7)] =
                f2bf(gelu_f(accI[ct][rt][i] + bi));
        }
    }
    __syncthreads();

    // ---- layer out: [R,512] @ Wout + bias + residual -> sYF ----
    f32x4 accO[2];
    accO[0] = (f32x4){0.f, 0.f, 0.f, 0.f};
    accO[1] = accO[0];
#pragma unroll
    for (int kt = 0; kt < 16; ++kt) {
      const int kcg = kt * 4 + g;
      short8v bfr = ld8(Woutp + (kcg * 128 + colbase) * 8);
#pragma unroll
      for (int rt = 0; rt < 2; ++rt) {
        const int row = rt * 16 + lr;
        short8v a = (row < R)
            ? ld8(sHf + row * 512 + (((kcg & 48) | ((kcg ^ row) & 15)) << 3))
            : (short8v){0, 0, 0, 0, 0, 0, 0, 0};
        accO[rt] = MFMA16(a, bfr, accO[rt]);
      }
    }
    {
      const float bo = bout[colbase];
#pragma unroll
      for (int rt = 0; rt < 2; ++rt)
#pragma unroll
        for (int i = 0; i < 4; ++i) {
          const int row = rt * 16 + g * 4 + i;
          if (row < R)
            sYF[row * 132 + colbase] =
                accO[rt][i] + bo + sHmidF[row * 132 + colbase];
        }
    }
    __syncthreads();

    // ---- LN2 + mask_V + store ----
    if (tid < R * 16) {
      const int row = tid >> 4, qq = tid & 15;
      const float* yr = sYF + row * 132 + qq * 8;
      float vals[8];
      float s = 0.f, qs = 0.f;
#pragma unroll
      for (int j = 0; j < 8; ++j) { float x = yr[j]; vals[j] = x; s += x; qs += x * x; }
      s += __shfl_xor(s, 1, 64);  qs += __shfl_xor(qs, 1, 64);
      s += __shfl_xor(s, 2, 64);  qs += __shfl_xor(qs, 2, 64);
      s += __shfl_xor(s, 4, 64);  qs += __shfl_xor(qs, 4, 64);
      s += __shfl_xor(s, 8, 64);  qs += __shfl_xor(qs, 8, 64);
      const float mean = s * (1.f / 128.f);
      const float var = qs * (1.f / 128.f) - mean * mean;
      const float rs = rsqrtf(var + 1e-5f);
      const int n = 2 * (bId + (row >> 1) * stride) + (row & 1);
      if (n < N) {
        const float mv = maskV[n];
#pragma unroll
        for (int j = 0; j < 8; ++j) {
          const int col = qq * 8 + j;
          out[(size_t)n * NH + col] =
              ((vals[j] - mean) * rs * g2[col] + be2[col]) * mv;
        }
      }
    }
  }
}

extern "C" void kernel_launch(void* const* d_in, const int* in_sizes, int n_in,
                              void* d_out, int out_size, void* d_ws, size_t ws_size,
                              hipStream_t stream) {
  const float* hV   = (const float*)d_in[0];
  const float* hE   = (const float*)d_in[1];
  const float* mV   = (const float*)d_in[2];
  const float* mAtt = (const float*)d_in[3];
  const float* W1   = (const float*)d_in[4];
  const float* b1   = (const float*)d_in[5];
  const float* W2   = (const float*)d_in[6];
  const float* b2   = (const float*)d_in[7];
  const float* W3   = (const float*)d_in[8];
  const float* b3   = (const float*)d_in[9];
  const float* g1   = (const float*)d_in[10];
  const float* be1  = (const float*)d_in[11];
  const float* Win  = (const float*)d_in[12];
  const float* binf = (const float*)d_in[13];
  const float* Wout = (const float*)d_in[14];
  const float* bout = (const float*)d_in[15];
  const float* g2   = (const float*)d_in[16];
  const float* be2  = (const float*)d_in[17];

  const int N = in_sizes[0] / NH;

  ushort* wsu = (ushort*)d_ws;   // packed weights: 448 KB

  pack_w<<<896, 256, 0, stream>>>(W1, W2, W3, Win, Wout, wsu);

  const int pairs = (N + 1) / 2;
  int grid = 512;                               // 2 blocks/CU persistent
  if ((pairs + grid - 1) / grid > 10)           // keep R = 2T <= 20 rows
    grid = (pairs + 9) / 10;

  msg_ffn<<<grid, 512, 0, stream>>>(hV, hE, mV, mAtt, wsu, b1, b2, b3, g1,
                                    be1, binf, bout, g2, be2, (float*)d_out, N);
  (void)n_in; (void)out_size; (void)ws_size;
}

// Round 4
// 336.772 us; speedup vs baseline: 1.3147x; 1.3147x over previous
//
#include <hip/hip_runtime.h>
#include <hip/hip_bf16.h>

#define NH 128   // hidden
#define NC 384   // edge feature dim
#define NK 32    // neighbors

typedef __attribute__((ext_vector_type(8))) short short8v;   // 8 bf16
typedef __attribute__((ext_vector_type(4))) float f32x4;

#define MFMA16(a, b, c) __builtin_amdgcn_mfma_f32_16x16x32_bf16((a), (b), (c), 0, 0, 0)

__device__ __forceinline__ ushort f2bf(float x) {
  __hip_bfloat16 h = __float2bfloat16(x);   // RNE; compiler packs to v_cvt_pk_bf16_f32
  ushort u;
  __builtin_memcpy(&u, &h, 2);
  return u;
}

__device__ __forceinline__ short8v ld8(const ushort* p) {
  return *reinterpret_cast<const short8v*>(p);
}
__device__ __forceinline__ void st8(ushort* p, short8v v) {
  *reinterpret_cast<short8v*>(p) = v;
}

__device__ __forceinline__ short8v pack8(float4 a, float4 b) {
  short8v v;
  v[0] = (short)f2bf(a.x); v[1] = (short)f2bf(a.y);
  v[2] = (short)f2bf(a.z); v[3] = (short)f2bf(a.w);
  v[4] = (short)f2bf(b.x); v[5] = (short)f2bf(b.y);
  v[6] = (short)f2bf(b.z); v[7] = (short)f2bf(b.w);
  return v;
}

// gelu(x) = x * sigmoid(x*(1.5958 + 0.07136 x^2)); |err| vs erf-GELU < 1e-3
__device__ __forceinline__ float gelu_f(float x) {
  float x2 = x * x;
  float m = __builtin_fmaf(0.07135481283f, x2, 1.595769122f);
  float e = __expf(-x * m);
  return x * __builtin_amdgcn_rcpf(1.0f + e);
}

// ---------------------------------------------------------------------------
// Weight packing: src row-major [k][col] f32 -> bf16 [k/8][col][k%8]
// ushort offsets: W1p 0 (64Ki), W2p 65536 (16Ki), W3p 81920 (16Ki),
// Winp 98304 (64Ki), Woutp 163840 (64Ki). Total 448 KB.
// ---------------------------------------------------------------------------
__global__ __launch_bounds__(256) void pack_w(
    const float* __restrict__ W1, const float* __restrict__ W2,
    const float* __restrict__ W3, const float* __restrict__ Win,
    const float* __restrict__ Wout, ushort* __restrict__ ws) {
  int id = blockIdx.x * 256 + threadIdx.x;
  if (id < 65536) {                       // W1: K=512, ncol=128
    int t = id, k = t >> 7, c = t & 127;
    ws[(((k >> 3) << 7) + c) * 8 + (k & 7)] = f2bf(W1[t]);
  } else if (id < 81920) {                // W2
    int t = id - 65536, k = t >> 7, c = t & 127;
    ws[65536 + (((k >> 3) << 7) + c) * 8 + (k & 7)] = f2bf(W2[t]);
  } else if (id < 98304) {                // W3
    int t = id - 81920, k = t >> 7, c = t & 127;
    ws[81920 + (((k >> 3) << 7) + c) * 8 + (k & 7)] = f2bf(W3[t]);
  } else if (id < 163840) {               // Win: K=128, ncol=512
    int t = id - 98304, k = t >> 9, c = t & 511;
    ws[98304 + (((k >> 3) << 9) + c) * 8 + (k & 7)] = f2bf(Win[t]);
  } else {                                // Wout: K=512, ncol=128
    int t = id - 163840, k = t >> 7, c = t & 127;
    ws[163840 + (((k >> 3) << 7) + c) * 8 + (k & 7)] = f2bf(Wout[t]);
  }
}

// ---------- msg helpers (free functions, small fixed register footprint) ----

__device__ __forceinline__ void load_chunk(const float* __restrict__ hE,
    int pr, int chunk, int snode, int sedge, int scb, int N,
    float4& L0, float4& L1, float4& L2, float4& L3) {
  int n = 2 * pr + snode;
  int nc = n < N ? n : 0;
  const float* base = hE + ((size_t)nc * NK + sedge) * NC + chunk * 128;
  const float4* p0 = reinterpret_cast<const float4*>(base + scb * 8);
  const float4* p1 = reinterpret_cast<const float4*>(base + 64 + scb * 8);
  L0 = p0[0]; L1 = p0[1]; L2 = p1[0]; L3 = p1[1];
}

__device__ __forceinline__ void write_chunk(ushort* __restrict__ buf,
    float4 L0, float4 L1, float4 L2, float4 L3,
    int srow, int scb, int rsw, bool zz) {
  short8v v0, v1;
  if (zz) {
    v0 = (short8v){0, 0, 0, 0, 0, 0, 0, 0};
    v1 = v0;
  } else {
    v0 = pack8(L0, L1);
    v1 = pack8(L2, L3);
  }
  st8(buf + srow * 128 + ((scb ^ rsw) << 3), v0);
  st8(buf + srow * 128 + (((scb + 8) ^ rsw) << 3), v1);
}

__device__ __forceinline__ void mfma_chunk(const ushort* __restrict__ buf,
    const ushort* __restrict__ Wp, int ktBase, f32x4 acc[4],
    int g, int lr, int colbase) {
#pragma unroll
  for (int j = 0; j < 4; ++j) {
    short8v b = ld8(Wp + (((ktBase + j) * 4 + g) * 128 + colbase) * 8);
    const int kcg = j * 4 + g;
#pragma unroll
    for (int rt = 0; rt < 4; ++rt) {
      const int row = rt * 16 + lr;
      short8v a = ld8(buf + row * 128 + ((kcg ^ (row & 15)) << 3));
      acc[rt] = MFMA16(a, b, acc[rt]);
    }
  }
}

__device__ __forceinline__ void epi_store(ushort* __restrict__ buf,
    const f32x4 acc[4], const float* __restrict__ bias, int colbase, int g) {
  const float bs = bias[colbase];
#pragma unroll
  for (int rt = 0; rt < 4; ++rt)
#pragma unroll
    for (int i = 0; i < 4; ++i) {
      const int rr = rt * 16 + g * 4 + i;
      buf[rr * 128 + ((((colbase >> 3) ^ (rr & 15)) << 3) | (colbase & 7))] =
          f2bf(gelu_f(acc[rt][i] + bs));
    }
}

// ---------------------------------------------------------------------------
// Persistent message kernel: 512 blocks x 512 threads, ~10 pairs each.
// Per pair: layer-1 over K=512 via 3x128-col chunks double-buffered in
// sA/sB; next pair's chunks 0/1 issued during layers 2/3 so the memory
// pipe stays busy across the compute tail. Max ~48 staging VGPR live.
// LDS ~34KB: sA/sB 16KB each (chunks, then H1/H2 alias them).
// ---------------------------------------------------------------------------
__global__ __launch_bounds__(512, 4) void msg_pers(
    const float* __restrict__ hV, const float* __restrict__ hE,
    const float* __restrict__ mAtt, const ushort* __restrict__ wsu,
    const float* __restrict__ b1, const float* __restrict__ b2,
    const float* __restrict__ b3, const float* __restrict__ g1,
    const float* __restrict__ be1, float* __restrict__ hmidf,
    ushort* __restrict__ hmidb, int N) {
  const ushort* W1p = wsu;
  const ushort* W2p = wsu + 65536;
  const ushort* W3p = wsu + 81920;

  __shared__ ushort sA[8192];    // 16KB: c0, c2, then H2
  __shared__ ushort sB[8192];    // 16KB: c1, then H1
  __shared__ ushort sHV[256];    // 2 nodes x 128 bf16
  __shared__ float  sDh[256];
  __shared__ float  sRed[16];

  const int tid = threadIdx.x;
  const int w = tid >> 6, lane = tid & 63;
  const int g = lane >> 4, lr = lane & 15;
  const int colbase = (w << 4) + lr;

  const int srow = tid >> 3, scb = tid & 7;   // 64 rows x 8 threads
  const int snode = srow >> 5, sedge = srow & 31;
  const int rsw = srow & 15;

  const int pairs = (N + 1) >> 1;
  const int stride = gridDim.x;
  const int bId = blockIdx.x;
  const int T = (pairs - bId + stride - 1) / stride;   // grid <= pairs

  float4 rA0, rA1, rA2, rA3, rB0, rB1, rB2, rB3;
  float4 hv0 = (float4){0.f, 0.f, 0.f, 0.f}, hv1 = hv0;

  // ---- prologue: pair bId's chunks 0/1 + hV ----
  load_chunk(hE, bId, 0, snode, sedge, scb, N, rA0, rA1, rA2, rA3);
  load_chunk(hE, bId, 1, snode, sedge, scb, N, rB0, rB1, rB2, rB3);
  if (tid < 32) {
    const int nd = tid >> 4, c8 = tid & 15;
    const int n = 2 * bId + nd;
    const int ncl = n < N ? n : 0;
    const float4* hp = reinterpret_cast<const float4*>(hV + (size_t)ncl * NH + c8 * 8);
    float4 h0 = hp[0], h1 = hp[1];
    if (n >= N) { h0 = (float4){0.f, 0.f, 0.f, 0.f}; h1 = h0; }
    st8(sHV + nd * 128 + c8 * 8, pack8(h0, h1));
  }

  for (int t = 0; t < T; ++t) {
    const int p = bId + t * stride;
    const bool zz = (2 * p + snode) >= N;

    // top: commit staged chunks 0/1
    write_chunk(sA, rA0, rA1, rA2, rA3, srow, scb, rsw, zz);
    write_chunk(sB, rB0, rB1, rB2, rB3, srow, scb, rsw, zz);
    __syncthreads();

    // ===== phase 0: issue c2; hV part (kt 0..3) + chunk0 from sA =====
    float4 rC0, rC1, rC2, rC3;
    load_chunk(hE, p, 2, snode, sedge, scb, N, rC0, rC1, rC2, rC3);
    f32x4 acc[4];
#pragma unroll
    for (int rt = 0; rt < 4; ++rt) acc[rt] = (f32x4){0.f, 0.f, 0.f, 0.f};
#pragma unroll
    for (int kt = 0; kt < 4; ++kt) {
      short8v bfr = ld8(W1p + ((kt * 4 + g) * 128 + colbase) * 8);
      short8v a0 = ld8(sHV + kt * 32 + g * 8);
      short8v a1 = ld8(sHV + 128 + kt * 32 + g * 8);
      acc[0] = MFMA16(a0, bfr, acc[0]);
      acc[1] = MFMA16(a0, bfr, acc[1]);
      acc[2] = MFMA16(a1, bfr, acc[2]);
      acc[3] = MFMA16(a1, bfr, acc[3]);
    }
    mfma_chunk(sA, W1p, 4, acc, g, lr, colbase);
    __syncthreads();

    // ===== phase 1: chunk1 from sB; write c2 -> sA =====
    mfma_chunk(sB, W1p, 8, acc, g, lr, colbase);
    write_chunk(sA, rC0, rC1, rC2, rC3, srow, scb, rsw, zz);
    __syncthreads();

    // ===== phase 2: chunk2 from sA; H1 -> sB =====
    mfma_chunk(sA, W1p, 12, acc, g, lr, colbase);
    epi_store(sB, acc, b1, colbase, g);
    __syncthreads();

    // ===== layer 2: sB(H1) -> H2 -> sA; issue next pair c0 =====
    const int pn = bId + (t + 1) * stride;
    const int pnc = pn < pairs ? pn : bId;
    load_chunk(hE, pnc, 0, snode, sedge, scb, N, rA0, rA1, rA2, rA3);
    f32x4 acc2[4];
#pragma unroll
    for (int rt = 0; rt < 4; ++rt) acc2[rt] = (f32x4){0.f, 0.f, 0.f, 0.f};
    mfma_chunk(sB, W2p, 0, acc2, g, lr, colbase);
    epi_store(sA, acc2, b2, colbase, g);
    __syncthreads();

    // ===== layer 3: sA(H2) -> masked edge-sum; issue next c1 + hv =====
    load_chunk(hE, pnc, 1, snode, sedge, scb, N, rB0, rB1, rB2, rB3);
    if (tid < 32) {
      const int nd = tid >> 4, c8 = tid & 15;
      const int n = 2 * pnc + nd;
      const int ncl = n < N ? n : 0;
      const float4* hp = reinterpret_cast<const float4*>(hV + (size_t)ncl * NH + c8 * 8);
      hv0 = hp[0]; hv1 = hp[1];
      if (n >= N) { hv0 = (float4){0.f, 0.f, 0.f, 0.f}; hv1 = hv0; }
    }
    f32x4 acc3[4];
#pragma unroll
    for (int rt = 0; rt < 4; ++rt) acc3[rt] = (f32x4){0.f, 0.f, 0.f, 0.f};
    mfma_chunk(sA, W3p, 0, acc3, g, lr, colbase);
    {
      const float bias = b3[colbase];
      float ns0 = 0.f, ns1 = 0.f;
#pragma unroll
      for (int rt = 0; rt < 4; ++rt) {
        const int nd = rt >> 1;
        float s = 0.f;
#pragma unroll
        for (int i = 0; i < 4; ++i) {
          const int e2 = (rt & 1) * 16 + g * 4 + i;
          const float m =
              (2 * p + nd < N) ? mAtt[(size_t)(2 * p + nd) * NK + e2] : 0.f;
          s += (acc3[rt][i] + bias) * m;
        }
        s += __shfl_xor(s, 16, 64);
        s += __shfl_xor(s, 32, 64);
        if (rt < 2) ns0 += s; else ns1 += s;
      }
      if (g == 0) { sDh[colbase] = ns0; sDh[128 + colbase] = ns1; }
    }
    __syncthreads();

    // ===== LN1 + h_mid store; stage next hv -> sHV =====
    float x_ln = 0.f;
    if (tid < 256) {
      const int nd = tid >> 7, i = tid & 127;
      const int gn = 2 * p + nd;
      if (gn < N)
        x_ln = hV[(size_t)gn * NH + i] + sDh[nd * NH + i] * (1.f / 30.f);
      float s = x_ln, qv = x_ln * x_ln;
#pragma unroll
      for (int d = 1; d < 64; d <<= 1) {
        s += __shfl_xor(s, d, 64);
        qv += __shfl_xor(qv, d, 64);
      }
      if (lane == 0) { sRed[w * 2] = s; sRed[w * 2 + 1] = qv; }
    }
    if (tid < 32) {
      const int nd = tid >> 4, c8 = tid & 15;
      st8(sHV + nd * 128 + c8 * 8, pack8(hv0, hv1));
    }
    __syncthreads();
    if (tid < 256) {
      const int nd = tid >> 7, i = tid & 127;
      const int gn = 2 * p + nd;
      if (gn < N) {
        const int wb = nd * 2;
        const float s = sRed[wb * 2] + sRed[wb * 2 + 2];
        const float qv = sRed[wb * 2 + 1] + sRed[wb * 2 + 3];
        const float mean = s * (1.f / 128.f);
        const float var = qv * (1.f / 128.f) - mean * mean;
        const float y = (x_ln - mean) * rsqrtf(var + 1e-5f) * g1[i] + be1[i];
        hmidf[(size_t)gn * NH + i] = y;
        hmidb[(size_t)gn * NH + i] = f2bf(y);
      }
    }
    __syncthreads();
  }
}

// ---------------------------------------------------------------------------
// FFN kernel: 16 nodes / block (625 blocks), 256 threads (4 waves).
// gelu(X @ Win) @ Wout + bias + residual -> LN2 -> *mask_V -> out (f32)
// ---------------------------------------------------------------------------
__global__ __launch_bounds__(256, 4) void ffn_kernel(
    const ushort* __restrict__ wsu, const float* __restrict__ binf,
    const float* __restrict__ boutf, const float* __restrict__ g2,
    const float* __restrict__ be2, const float* __restrict__ maskV,
    const float* __restrict__ hmidf, const ushort* __restrict__ hmidb,
    float* __restrict__ out, int N) {
  const ushort* Winp = wsu + 98304;
  const ushort* Woutp = wsu + 163840;

  __shared__ ushort sX[16 * 128];     // 4KB
  __shared__ ushort sHf[16 * 512];    // 16KB
  __shared__ float  sY[16 * 132];     // 8.25KB

  const int tid = threadIdx.x;
  const int w = tid >> 6, lane = tid & 63;
  const int g = lane >> 4, lr = lane & 15;
  const int n0 = blockIdx.x * 16;

  // stage h_mid (bf16) -> sX swizzled (256 chunks, one per thread)
  {
    const int rr = tid >> 4, c8 = tid & 15;
    const int n = n0 + rr;
    short8v v = {0, 0, 0, 0, 0, 0, 0, 0};
    if (n < N) v = ld8(hmidb + (size_t)n * NH + c8 * 8);
    st8(sX + rr * 128 + ((c8 ^ (rr & 15)) << 3), v);
  }
  __syncthreads();

  // -------- layer in: [16,128] @ Win -> gelu -> sHf [16,512] --------
#pragma unroll
  for (int ct8 = 0; ct8 < 8; ++ct8) {
    const int col = (w * 8 + ct8) * 16 + lr;
    f32x4 a0acc = (f32x4){0.f, 0.f, 0.f, 0.f};
#pragma unroll
    for (int kt = 0; kt < 4; ++kt) {
      short8v b = ld8(Winp + ((kt * 4 + g) * 512 + col) * 8);
      const int kcg = kt * 4 + g;
      const int r0 = lr;
      short8v a0 = ld8(sX + r0 * 128 + ((kcg ^ (r0 & 15)) << 3));
      a0acc = MFMA16(a0, b, a0acc);
    }
    const float bi = binf[col];
#pragma unroll
    for (int i = 0; i < 4; ++i) {
      const int rr = g * 4 + i;
      const float v0 = gelu_f(a0acc[i] + bi);
      sHf[rr * 512 + ((((col >> 3) ^ (rr & 15)) << 3) | (col & 7))] = f2bf(v0);
    }
  }
  __syncthreads();

  // -------- layer out: [16,512] @ Wout (wave w -> cols [w*32, w*32+32)) -----
  f32x4 o0 = (f32x4){0.f, 0.f, 0.f, 0.f}, o1 = o0;
#pragma unroll
  for (int kt = 0; kt < 16; ++kt) {
    const int kcg = kt * 4 + g;                 // [0,64)
    const int c0 = (2 * w) * 16 + lr, c1 = (2 * w + 1) * 16 + lr;
    short8v b0 = ld8(Woutp + (kcg * 128 + c0) * 8);
    short8v b1 = ld8(Woutp + (kcg * 128 + c1) * 8);
    const int r0 = lr;
    short8v a0 = ld8(sHf + r0 * 512 + ((kcg ^ (r0 & 15)) << 3));
    o0 = MFMA16(a0, b0, o0);
    o1 = MFMA16(a0, b1, o1);
  }
  // epilogue: + bias + residual -> sY
#pragma unroll
  for (int ct = 0; ct < 2; ++ct) {
    const int col = (2 * w + ct) * 16 + lr;
    const float bo = boutf[col];
    const f32x4 oo = ct ? o1 : o0;
#pragma unroll
    for (int i = 0; i < 4; ++i) {
      const int rr = g * 4 + i;
      const int n = n0 + rr;
      const float resid = (n < N) ? hmidf[(size_t)n * NH + col] : 0.f;
      sY[rr * 132 + col] = oo[i] + bo + resid;
    }
  }
  __syncthreads();

  // -------- LN2 + mask + store (16 threads per row, 8 cols each) --------
  {
    const int rr = tid >> 4, qq = tid & 15;
    const int n = n0 + rr;
    float vals[8];
    float s = 0.f, qs = 0.f;
    const float* yr = sY + rr * 132 + qq * 8;
#pragma unroll
    for (int j = 0; j < 8; ++j) { float x = yr[j]; vals[j] = x; s += x; qs += x * x; }
    s += __shfl_xor(s, 1, 64);  qs += __shfl_xor(qs, 1, 64);
    s += __shfl_xor(s, 2, 64);  qs += __shfl_xor(qs, 2, 64);
    s += __shfl_xor(s, 4, 64);  qs += __shfl_xor(qs, 4, 64);
    s += __shfl_xor(s, 8, 64);  qs += __shfl_xor(qs, 8, 64);
    const float mean = s * (1.f / 128.f);
    const float var = qs * (1.f / 128.f) - mean * mean;
    const float rs = rsqrtf(var + 1e-5f);
    if (n < N) {
      const float mv = maskV[n];
#pragma unroll
      for (int j = 0; j < 8; ++j) {
        const int col = qq * 8 + j;
        out[(size_t)n * NH + col] = ((vals[j] - mean) * rs * g2[col] + be2[col]) * mv;
      }
    }
  }
}

extern "C" void kernel_launch(void* const* d_in, const int* in_sizes, int n_in,
                              void* d_out, int out_size, void* d_ws, size_t ws_size,
                              hipStream_t stream) {
  const float* hV   = (const float*)d_in[0];
  const float* hE   = (const float*)d_in[1];
  const float* mV   = (const float*)d_in[2];
  const float* mAtt = (const float*)d_in[3];
  const float* W1   = (const float*)d_in[4];
  const float* b1   = (const float*)d_in[5];
  const float* W2   = (const float*)d_in[6];
  const float* b2   = (const float*)d_in[7];
  const float* W3   = (const float*)d_in[8];
  const float* b3   = (const float*)d_in[9];
  const float* g1   = (const float*)d_in[10];
  const float* be1  = (const float*)d_in[11];
  const float* Win  = (const float*)d_in[12];
  const float* binf = (const float*)d_in[13];
  const float* Wout = (const float*)d_in[14];
  const float* bout = (const float*)d_in[15];
  const float* g2   = (const float*)d_in[16];
  const float* be2  = (const float*)d_in[17];

  const int N = in_sizes[0] / NH;

  ushort* wsu = (ushort*)d_ws;                         // packed weights: 448 KB
  float*  hmidf = (float*)((char*)d_ws + 458752);      // N*128 f32
  ushort* hmidb = (ushort*)((char*)d_ws + 458752 + (size_t)N * NH * 4);  // N*128 bf16

  pack_w<<<896, 256, 0, stream>>>(W1, W2, W3, Win, Wout, wsu);

  const int pairs = (N + 1) / 2;
  const int grid = pairs < 512 ? pairs : 512;
  msg_pers<<<grid, 512, 0, stream>>>(hV, hE, mAtt, wsu, b1, b2, b3, g1, be1,
                                     hmidf, hmidb, N);
  ffn_kernel<<<(N + 15) / 16, 256, 0, stream>>>(wsu, binf, bout, g2, be2, mV,
                                                hmidf, hmidb, (float*)d_out, N);
  (void)n_in; (void)out_size; (void)ws_size;
}

// Round 5
// 336.393 us; speedup vs baseline: 1.3162x; 1.0011x over previous
//
#include <hip/hip_runtime.h>
#include <hip/hip_bf16.h>

#define NH 128   // hidden
#define NC 384   // edge feature dim
#define NK 32    // neighbors

typedef __attribute__((ext_vector_type(8))) short short8v;   // 8 bf16
typedef __attribute__((ext_vector_type(4))) float f32x4;

#define MFMA16(a, b, c) __builtin_amdgcn_mfma_f32_16x16x32_bf16((a), (b), (c), 0, 0, 0)

__device__ __forceinline__ ushort f2bf(float x) {
  __hip_bfloat16 h = __float2bfloat16(x);   // RNE; compiler packs to v_cvt_pk_bf16_f32
  ushort u;
  __builtin_memcpy(&u, &h, 2);
  return u;
}

__device__ __forceinline__ short8v ld8(const ushort* p) {
  return *reinterpret_cast<const short8v*>(p);
}
__device__ __forceinline__ void st8(ushort* p, short8v v) {
  *reinterpret_cast<short8v*>(p) = v;
}

__device__ __forceinline__ short8v pack8(float4 a, float4 b) {
  short8v v;
  v[0] = (short)f2bf(a.x); v[1] = (short)f2bf(a.y);
  v[2] = (short)f2bf(a.z); v[3] = (short)f2bf(a.w);
  v[4] = (short)f2bf(b.x); v[5] = (short)f2bf(b.y);
  v[6] = (short)f2bf(b.z); v[7] = (short)f2bf(b.w);
  return v;
}

// gelu(x) = x * sigmoid(x*(1.5958 + 0.07136 x^2)); |err| vs erf-GELU < 1e-3
__device__ __forceinline__ float gelu_f(float x) {
  float x2 = x * x;
  float m = __builtin_fmaf(0.07135481283f, x2, 1.595769122f);
  float e = __expf(-x * m);
  return x * __builtin_amdgcn_rcpf(1.0f + e);
}

// ---------------------------------------------------------------------------
// Weight packing: src row-major [k][col] f32 -> bf16 [k/8][col][k%8]
// ushort offsets: W1p 0 (64Ki), W2p 65536 (16Ki), W3p 81920 (16Ki),
// Winp 98304 (64Ki), Woutp 163840 (64Ki). Total 448 KB.
// ---------------------------------------------------------------------------
__global__ __launch_bounds__(256) void pack_w(
    const float* __restrict__ W1, const float* __restrict__ W2,
    const float* __restrict__ W3, const float* __restrict__ Win,
    const float* __restrict__ Wout, ushort* __restrict__ ws) {
  int id = blockIdx.x * 256 + threadIdx.x;
  if (id < 65536) {                       // W1: K=512, ncol=128
    int t = id, k = t >> 7, c = t & 127;
    ws[(((k >> 3) << 7) + c) * 8 + (k & 7)] = f2bf(W1[t]);
  } else if (id < 81920) {                // W2
    int t = id - 65536, k = t >> 7, c = t & 127;
    ws[65536 + (((k >> 3) << 7) + c) * 8 + (k & 7)] = f2bf(W2[t]);
  } else if (id < 98304) {                // W3
    int t = id - 81920, k = t >> 7, c = t & 127;
    ws[81920 + (((k >> 3) << 7) + c) * 8 + (k & 7)] = f2bf(W3[t]);
  } else if (id < 163840) {               // Win: K=128, ncol=512
    int t = id - 98304, k = t >> 9, c = t & 511;
    ws[98304 + (((k >> 3) << 9) + c) * 8 + (k & 7)] = f2bf(Win[t]);
  } else {                                // Wout: K=512, ncol=128
    int t = id - 163840, k = t >> 7, c = t & 127;
    ws[163840 + (((k >> 3) << 7) + c) * 8 + (k & 7)] = f2bf(Wout[t]);
  }
}

// ---------- msg helpers ----------

__device__ __forceinline__ void load_chunk(const float* __restrict__ hE,
    int pr, int chunk, int snode, int sedge, int scb, int N,
    float4& L0, float4& L1, float4& L2, float4& L3) {
  int n = 2 * pr + snode;
  int nc = n < N ? n : 0;
  const float* base = hE + ((size_t)nc * NK + sedge) * NC + chunk * 128;
  const float4* p0 = reinterpret_cast<const float4*>(base + scb * 8);
  const float4* p1 = reinterpret_cast<const float4*>(base + 64 + scb * 8);
  L0 = p0[0]; L1 = p0[1]; L2 = p1[0]; L3 = p1[1];
}

__device__ __forceinline__ void write_chunk(ushort* __restrict__ buf,
    float4 L0, float4 L1, float4 L2, float4 L3,
    int srow, int scb, int rsw, bool zz) {
  short8v v0, v1;
  if (zz) {
    v0 = (short8v){0, 0, 0, 0, 0, 0, 0, 0};
    v1 = v0;
  } else {
    v0 = pack8(L0, L1);
    v1 = pack8(L2, L3);
  }
  st8(buf + srow * 128 + ((scb ^ rsw) << 3), v0);
  st8(buf + srow * 128 + (((scb + 8) ^ rsw) << 3), v1);
}

__device__ __forceinline__ void mfma_chunk(const ushort* __restrict__ buf,
    const ushort* __restrict__ Wp, int ktBase, f32x4 acc[4],
    int g, int lr, int colbase) {
#pragma unroll
  for (int j = 0; j < 4; ++j) {
    short8v b = ld8(Wp + (((ktBase + j) * 4 + g) * 128 + colbase) * 8);
    const int kcg = j * 4 + g;
#pragma unroll
    for (int rt = 0; rt < 4; ++rt) {
      const int row = rt * 16 + lr;
      short8v a = ld8(buf + row * 128 + ((kcg ^ (row & 15)) << 3));
      acc[rt] = MFMA16(a, b, acc[rt]);
    }
  }
}

__device__ __forceinline__ void epi_store(ushort* __restrict__ buf,
    const f32x4 acc[4], const float* __restrict__ bias, int colbase, int g) {
  const float bs = bias[colbase];
#pragma unroll
  for (int rt = 0; rt < 4; ++rt)
#pragma unroll
    for (int i = 0; i < 4; ++i) {
      const int rr = rt * 16 + g * 4 + i;
      buf[rr * 128 + ((((colbase >> 3) ^ (rr & 15)) << 3) | (colbase & 7))] =
          f2bf(gelu_f(acc[rt][i] + bs));
    }
}

// ---------------------------------------------------------------------------
// Persistent message kernel: 512 blocks x 512 threads, ~10 pairs each.
// SINGLE acc[4] reused across the three layers (sequential) -> accumulator
// footprint 16 unified regs instead of 48-64, so staging never spills.
// ---------------------------------------------------------------------------
__global__ __launch_bounds__(512, 4) void msg_pers(
    const float* __restrict__ hV, const float* __restrict__ hE,
    const float* __restrict__ mAtt, const ushort* __restrict__ wsu,
    const float* __restrict__ b1, const float* __restrict__ b2,
    const float* __restrict__ b3, const float* __restrict__ g1,
    const float* __restrict__ be1, float* __restrict__ hmidf,
    ushort* __restrict__ hmidb, int N) {
  const ushort* W1p = wsu;
  const ushort* W2p = wsu + 65536;
  const ushort* W3p = wsu + 81920;

  __shared__ ushort sA[8192];    // 16KB: c0, c2, then H2
  __shared__ ushort sB[8192];    // 16KB: c1, then H1
  __shared__ ushort sHV[256];    // 2 nodes x 128 bf16
  __shared__ float  sDh[256];
  __shared__ float  sRed[16];

  const int tid = threadIdx.x;
  const int w = tid >> 6, lane = tid & 63;
  const int g = lane >> 4, lr = lane & 15;
  const int colbase = (w << 4) + lr;

  const int srow = tid >> 3, scb = tid & 7;   // 64 rows x 8 threads
  const int snode = srow >> 5, sedge = srow & 31;
  const int rsw = srow & 15;

  const int pairs = (N + 1) >> 1;
  const int stride = gridDim.x;
  const int bId = blockIdx.x;
  const int T = (pairs - bId + stride - 1) / stride;   // grid <= pairs

  float4 rA0, rA1, rA2, rA3, rB0, rB1, rB2, rB3;
  float4 hv0 = (float4){0.f, 0.f, 0.f, 0.f}, hv1 = hv0;

  // ---- prologue: pair bId's chunks 0/1 + hV ----
  load_chunk(hE, bId, 0, snode, sedge, scb, N, rA0, rA1, rA2, rA3);
  load_chunk(hE, bId, 1, snode, sedge, scb, N, rB0, rB1, rB2, rB3);
  if (tid < 32) {
    const int nd = tid >> 4, c8 = tid & 15;
    const int n = 2 * bId + nd;
    const int ncl = n < N ? n : 0;
    const float4* hp = reinterpret_cast<const float4*>(hV + (size_t)ncl * NH + c8 * 8);
    float4 h0 = hp[0], h1 = hp[1];
    if (n >= N) { h0 = (float4){0.f, 0.f, 0.f, 0.f}; h1 = h0; }
    st8(sHV + nd * 128 + c8 * 8, pack8(h0, h1));
  }

  f32x4 acc[4];   // ONE accumulator array, reused by all three layers

  for (int t = 0; t < T; ++t) {
    const int p = bId + t * stride;
    const bool zz = (2 * p + snode) >= N;

    // top: commit staged chunks 0/1
    write_chunk(sA, rA0, rA1, rA2, rA3, srow, scb, rsw, zz);
    write_chunk(sB, rB0, rB1, rB2, rB3, srow, scb, rsw, zz);
    __syncthreads();

    // ===== phase 0: issue c2; hV part (kt 0..3) + chunk0 from sA =====
    float4 rC0, rC1, rC2, rC3;
    load_chunk(hE, p, 2, snode, sedge, scb, N, rC0, rC1, rC2, rC3);
#pragma unroll
    for (int rt = 0; rt < 4; ++rt) acc[rt] = (f32x4){0.f, 0.f, 0.f, 0.f};
#pragma unroll
    for (int kt = 0; kt < 4; ++kt) {
      short8v bfr = ld8(W1p + ((kt * 4 + g) * 128 + colbase) * 8);
      short8v a0 = ld8(sHV + kt * 32 + g * 8);
      short8v a1 = ld8(sHV + 128 + kt * 32 + g * 8);
      acc[0] = MFMA16(a0, bfr, acc[0]);
      acc[1] = MFMA16(a0, bfr, acc[1]);
      acc[2] = MFMA16(a1, bfr, acc[2]);
      acc[3] = MFMA16(a1, bfr, acc[3]);
    }
    mfma_chunk(sA, W1p, 4, acc, g, lr, colbase);
    __syncthreads();

    // ===== phase 1: chunk1 from sB; write c2 -> sA =====
    mfma_chunk(sB, W1p, 8, acc, g, lr, colbase);
    write_chunk(sA, rC0, rC1, rC2, rC3, srow, scb, rsw, zz);
    __syncthreads();

    // ===== phase 2: chunk2 from sA; H1 -> sB =====
    mfma_chunk(sA, W1p, 12, acc, g, lr, colbase);
    epi_store(sB, acc, b1, colbase, g);
    __syncthreads();

    // ===== layer 2: sB(H1) -> H2 -> sA; issue next pair c0 =====
    const int pn = bId + (t + 1) * stride;
    const int pnc = pn < pairs ? pn : bId;
    load_chunk(hE, pnc, 0, snode, sedge, scb, N, rA0, rA1, rA2, rA3);
#pragma unroll
    for (int rt = 0; rt < 4; ++rt) acc[rt] = (f32x4){0.f, 0.f, 0.f, 0.f};
    mfma_chunk(sB, W2p, 0, acc, g, lr, colbase);
    epi_store(sA, acc, b2, colbase, g);
    __syncthreads();

    // ===== layer 3: sA(H2) -> masked edge-sum; issue next c1 + hv =====
    load_chunk(hE, pnc, 1, snode, sedge, scb, N, rB0, rB1, rB2, rB3);
    if (tid < 32) {
      const int nd = tid >> 4, c8 = tid & 15;
      const int n = 2 * pnc + nd;
      const int ncl = n < N ? n : 0;
      const float4* hp = reinterpret_cast<const float4*>(hV + (size_t)ncl * NH + c8 * 8);
      hv0 = hp[0]; hv1 = hp[1];
      if (n >= N) { hv0 = (float4){0.f, 0.f, 0.f, 0.f}; hv1 = hv0; }
    }
#pragma unroll
    for (int rt = 0; rt < 4; ++rt) acc[rt] = (f32x4){0.f, 0.f, 0.f, 0.f};
    mfma_chunk(sA, W3p, 0, acc, g, lr, colbase);
    {
      const float bias = b3[colbase];
      float ns0 = 0.f, ns1 = 0.f;
#pragma unroll
      for (int rt = 0; rt < 4; ++rt) {
        const int nd = rt >> 1;
        float s = 0.f;
#pragma unroll
        for (int i = 0; i < 4; ++i) {
          const int e2 = (rt & 1) * 16 + g * 4 + i;
          const float m =
              (2 * p + nd < N) ? mAtt[(size_t)(2 * p + nd) * NK + e2] : 0.f;
          s += (acc[rt][i] + bias) * m;
        }
        s += __shfl_xor(s, 16, 64);
        s += __shfl_xor(s, 32, 64);
        if (rt < 2) ns0 += s; else ns1 += s;
      }
      if (g == 0) { sDh[colbase] = ns0; sDh[128 + colbase] = ns1; }
    }
    __syncthreads();

    // ===== LN1 + h_mid store; stage next hv -> sHV =====
    float x_ln = 0.f;
    if (tid < 256) {
      const int nd = tid >> 7, i = tid & 127;
      const int gn = 2 * p + nd;
      if (gn < N)
        x_ln = hV[(size_t)gn * NH + i] + sDh[nd * NH + i] * (1.f / 30.f);
      float s = x_ln, qv = x_ln * x_ln;
#pragma unroll
      for (int d = 1; d < 64; d <<= 1) {
        s += __shfl_xor(s, d, 64);
        qv += __shfl_xor(qv, d, 64);
      }
      if (lane == 0) { sRed[w * 2] = s; sRed[w * 2 + 1] = qv; }
    }
    if (tid < 32) {
      const int nd = tid >> 4, c8 = tid & 15;
      st8(sHV + nd * 128 + c8 * 8, pack8(hv0, hv1));
    }
    __syncthreads();
    if (tid < 256) {
      const int nd = tid >> 7, i = tid & 127;
      const int gn = 2 * p + nd;
      if (gn < N) {
        const int wb = nd * 2;
        const float s = sRed[wb * 2] + sRed[wb * 2 + 2];
        const float qv = sRed[wb * 2 + 1] + sRed[wb * 2 + 3];
        const float mean = s * (1.f / 128.f);
        const float var = qv * (1.f / 128.f) - mean * mean;
        const float y = (x_ln - mean) * rsqrtf(var + 1e-5f) * g1[i] + be1[i];
        hmidf[(size_t)gn * NH + i] = y;
        hmidb[(size_t)gn * NH + i] = f2bf(y);
      }
    }
    __syncthreads();
  }
}

// ---------------------------------------------------------------------------
// FFN kernel: 16 nodes / block (625 blocks), 256 threads (4 waves).
// ---------------------------------------------------------------------------
__global__ __launch_bounds__(256, 4) void ffn_kernel(
    const ushort* __restrict__ wsu, const float* __restrict__ binf,
    const float* __restrict__ boutf, const float* __restrict__ g2,
    const float* __restrict__ be2, const float* __restrict__ maskV,
    const float* __restrict__ hmidf, const ushort* __restrict__ hmidb,
    float* __restrict__ out, int N) {
  const ushort* Winp = wsu + 98304;
  const ushort* Woutp = wsu + 163840;

  __shared__ ushort sX[16 * 128];     // 4KB
  __shared__ ushort sHf[16 * 512];    // 16KB
  __shared__ float  sY[16 * 132];     // 8.25KB

  const int tid = threadIdx.x;
  const int w = tid >> 6, lane = tid & 63;
  const int g = lane >> 4, lr = lane & 15;
  const int n0 = blockIdx.x * 16;

  // stage h_mid (bf16) -> sX swizzled (256 chunks, one per thread)
  {
    const int rr = tid >> 4, c8 = tid & 15;
    const int n = n0 + rr;
    short8v v = {0, 0, 0, 0, 0, 0, 0, 0};
    if (n < N) v = ld8(hmidb + (size_t)n * NH + c8 * 8);
    st8(sX + rr * 128 + ((c8 ^ (rr & 15)) << 3), v);
  }
  __syncthreads();

  // -------- layer in: [16,128] @ Win -> gelu -> sHf [16,512] --------
#pragma unroll
  for (int ct8 = 0; ct8 < 8; ++ct8) {
    const int col = (w * 8 + ct8) * 16 + lr;
    f32x4 a0acc = (f32x4){0.f, 0.f, 0.f, 0.f};
#pragma unroll
    for (int kt = 0; kt < 4; ++kt) {
      short8v b = ld8(Winp + ((kt * 4 + g) * 512 + col) * 8);
      const int kcg = kt * 4 + g;
      const int r0 = lr;
      short8v a0 = ld8(sX + r0 * 128 + ((kcg ^ (r0 & 15)) << 3));
      a0acc = MFMA16(a0, b, a0acc);
    }
    const float bi = binf[col];
#pragma unroll
    for (int i = 0; i < 4; ++i) {
      const int rr = g * 4 + i;
      const float v0 = gelu_f(a0acc[i] + bi);
      sHf[rr * 512 + ((((col >> 3) ^ (rr & 15)) << 3) | (col & 7))] = f2bf(v0);
    }
  }
  __syncthreads();

  // -------- layer out: [16,512] @ Wout (wave w -> cols [w*32, w*32+32)) -----
  f32x4 o0 = (f32x4){0.f, 0.f, 0.f, 0.f}, o1 = o0;
#pragma unroll
  for (int kt = 0; kt < 16; ++kt) {
    const int kcg = kt * 4 + g;                 // [0,64)
    const int c0 = (2 * w) * 16 + lr, c1 = (2 * w + 1) * 16 + lr;
    short8v b0 = ld8(Woutp + (kcg * 128 + c0) * 8);
    short8v b1 = ld8(Woutp + (kcg * 128 + c1) * 8);
    const int r0 = lr;
    short8v a0 = ld8(sHf + r0 * 512 + ((kcg ^ (r0 & 15)) << 3));
    o0 = MFMA16(a0, b0, o0);
    o1 = MFMA16(a0, b1, o1);
  }
  // epilogue: + bias + residual -> sY
#pragma unroll
  for (int ct = 0; ct < 2; ++ct) {
    const int col = (2 * w + ct) * 16 + lr;
    const float bo = boutf[col];
    const f32x4 oo = ct ? o1 : o0;
#pragma unroll
    for (int i = 0; i < 4; ++i) {
      const int rr = g * 4 + i;
      const int n = n0 + rr;
      const float resid = (n < N) ? hmidf[(size_t)n * NH + col] : 0.f;
      sY[rr * 132 + col] = oo[i] + bo + resid;
    }
  }
  __syncthreads();

  // -------- LN2 + mask + store (16 threads per row, 8 cols each) --------
  {
    const int rr = tid >> 4, qq = tid & 15;
    const int n = n0 + rr;
    float vals[8];
    float s = 0.f, qs = 0.f;
    const float* yr = sY + rr * 132 + qq * 8;
#pragma unroll
    for (int j = 0; j < 8; ++j) { float x = yr[j]; vals[j] = x; s += x; qs += x * x; }
    s += __shfl_xor(s, 1, 64);  qs += __shfl_xor(qs, 1, 64);
    s += __shfl_xor(s, 2, 64);  qs += __shfl_xor(qs, 2, 64);
    s += __shfl_xor(s, 4, 64);  qs += __shfl_xor(qs, 4, 64);
    s += __shfl_xor(s, 8, 64);  qs += __shfl_xor(qs, 8, 64);
    const float mean = s * (1.f / 128.f);
    const float var = qs * (1.f / 128.f) - mean * mean;
    const float rs = rsqrtf(var + 1e-5f);
    if (n < N) {
      const float mv = maskV[n];
#pragma unroll
      for (int j = 0; j < 8; ++j) {
        const int col = qq * 8 + j;
        out[(size_t)n * NH + col] = ((vals[j] - mean) * rs * g2[col] + be2[col]) * mv;
      }
    }
  }
}

extern "C" void kernel_launch(void* const* d_in, const int* in_sizes, int n_in,
                              void* d_out, int out_size, void* d_ws, size_t ws_size,
                              hipStream_t stream) {
  const float* hV   = (const float*)d_in[0];
  const float* hE   = (const float*)d_in[1];
  const float* mV   = (const float*)d_in[2];
  const float* mAtt = (const float*)d_in[3];
  const float* W1   = (const float*)d_in[4];
  const float* b1   = (const float*)d_in[5];
  const float* W2   = (const float*)d_in[6];
  const float* b2   = (const float*)d_in[7];
  const float* W3   = (const float*)d_in[8];
  const float* b3   = (const float*)d_in[9];
  const float* g1   = (const float*)d_in[10];
  const float* be1  = (const float*)d_in[11];
  const float* Win  = (const float*)d_in[12];
  const float* binf = (const float*)d_in[13];
  const float* Wout = (const float*)d_in[14];
  const float* bout = (const float*)d_in[15];
  const float* g2   = (const float*)d_in[16];
  const float* be2  = (const float*)d_in[17];

  const int N = in_sizes[0] / NH;

  ushort* wsu = (ushort*)d_ws;                         // packed weights: 448 KB
  float*  hmidf = (float*)((char*)d_ws + 458752);      // N*128 f32
  ushort* hmidb = (ushort*)((char*)d_ws + 458752 + (size_t)N * NH * 4);  // N*128 bf16

  pack_w<<<896, 256, 0, stream>>>(W1, W2, W3, Win, Wout, wsu);

  const int pairs = (N + 1) / 2;
  const int grid = pairs < 512 ? pairs : 512;
  msg_pers<<<grid, 512, 0, stream>>>(hV, hE, mAtt, wsu, b1, b2, b3, g1, be1,
                                     hmidf, hmidb, N);
  ffn_kernel<<<(N + 15) / 16, 256, 0, stream>>>(wsu, binf, bout, g2, be2, mV,
                                                hmidf, hmidb, (float*)d_out, N);
  (void)n_in; (void)out_size; (void)ws_size;
}

// Round 6
// 183.982 us; speedup vs baseline: 2.4066x; 1.8284x over previous
//
#include <hip/hip_runtime.h>
#include <hip/hip_bf16.h>

#define NH 128   // hidden
#define NC 384   // edge feature dim
#define NK 32    // neighbors

typedef __attribute__((ext_vector_type(8))) short short8v;   // 8 bf16
typedef __attribute__((ext_vector_type(4))) float f32x4;

#define MFMA16(a, b, c) __builtin_amdgcn_mfma_f32_16x16x32_bf16((a), (b), (c), 0, 0, 0)

__device__ __forceinline__ ushort f2bf(float x) {
  __hip_bfloat16 h = __float2bfloat16(x);   // RNE; packs to v_cvt_pk_bf16_f32
  ushort u;
  __builtin_memcpy(&u, &h, 2);
  return u;
}

__device__ __forceinline__ short8v ld8(const ushort* p) {
  return *reinterpret_cast<const short8v*>(p);
}
__device__ __forceinline__ void st8(ushort* p, short8v v) {
  *reinterpret_cast<short8v*>(p) = v;
}

__device__ __forceinline__ short8v pack8(float4 a, float4 b) {
  short8v v;
  v[0] = (short)f2bf(a.x); v[1] = (short)f2bf(a.y);
  v[2] = (short)f2bf(a.z); v[3] = (short)f2bf(a.w);
  v[4] = (short)f2bf(b.x); v[5] = (short)f2bf(b.y);
  v[6] = (short)f2bf(b.z); v[7] = (short)f2bf(b.w);
  return v;
}

// gelu(x) = x * sigmoid(x*(1.5958 + 0.07136 x^2)); |err| vs erf-GELU < 1e-3
__device__ __forceinline__ float gelu_f(float x) {
  float x2 = x * x;
  float m = __builtin_fmaf(0.07135481283f, x2, 1.595769122f);
  float e = __expf(-x * m);
  return x * __builtin_amdgcn_rcpf(1.0f + e);
}

// async 16B HBM -> LDS (no VGPR data path)
__device__ __forceinline__ void gload_lds16(const float* g, float* l) {
  __builtin_amdgcn_global_load_lds(
      (const __attribute__((address_space(1))) unsigned int*)g,
      (__attribute__((address_space(3))) unsigned int*)l, 16, 0, 0);
}

// ---------------------------------------------------------------------------
// Weight packing: src row-major [k][col] f32 -> bf16 [k/8][col][k%8]
// ushort offsets: W1p 0 (64Ki), W2p 65536 (16Ki), W3p 81920 (16Ki),
// Winp 98304 (64Ki), Woutp 163840 (64Ki). Total 448 KB.
// ---------------------------------------------------------------------------
__global__ __launch_bounds__(256) void pack_w(
    const float* __restrict__ W1, const float* __restrict__ W2,
    const float* __restrict__ W3, const float* __restrict__ Win,
    const float* __restrict__ Wout, ushort* __restrict__ ws) {
  int id = blockIdx.x * 256 + threadIdx.x;
  if (id < 65536) {                       // W1: K=512, ncol=128
    int t = id, k = t >> 7, c = t & 127;
    ws[(((k >> 3) << 7) + c) * 8 + (k & 7)] = f2bf(W1[t]);
  } else if (id < 81920) {                // W2
    int t = id - 65536, k = t >> 7, c = t & 127;
    ws[65536 + (((k >> 3) << 7) + c) * 8 + (k & 7)] = f2bf(W2[t]);
  } else if (id < 98304) {                // W3
    int t = id - 81920, k = t >> 7, c = t & 127;
    ws[81920 + (((k >> 3) << 7) + c) * 8 + (k & 7)] = f2bf(W3[t]);
  } else if (id < 163840) {               // Win: K=128, ncol=512
    int t = id - 98304, k = t >> 9, c = t & 511;
    ws[98304 + (((k >> 3) << 9) + c) * 8 + (k & 7)] = f2bf(Win[t]);
  } else {                                // Wout: K=512, ncol=128
    int t = id - 163840, k = t >> 7, c = t & 127;
    ws[163840 + (((k >> 3) << 7) + c) * 8 + (k & 7)] = f2bf(Wout[t]);
  }
}

// ---------- msg helpers ----------

// Issue async stage of chunk (128 f32 cols) of pair p into sF (linear [64][128] f32).
// 4 instrs/wave; LDS dest = wave-uniform base + lane*16 (HW rule); global src per-lane.
__device__ __forceinline__ void stage_issue(const float* __restrict__ hE,
    float* sF, int p, int chunk, int tid, int N) {
  const int w = tid >> 6, l = tid & 63;
#pragma unroll
  for (int j = 0; j < 4; ++j) {
    const int base16 = j * 512 + w * 64;       // 16B units (wave-uniform)
    const int fidx = (base16 + l) * 4;         // this lane's f32 index
    const int row = fidx >> 7;                 // 0..63
    const int col = fidx & 127;
    const int node = row >> 5, e = row & 31;
    int n = 2 * p + node;
    if (n >= N) n = 0;                         // clamped; garbage masked later
    const float* g = hE + ((size_t)n * NK + e) * NC + chunk * 128 + col;
    gload_lds16(g, sF + base16 * 4);           // wave base; HW adds lane*16
  }
}

// Convert sF (linear f32) -> sB (bf16, XOR-swizzled granules). Each elem once.
__device__ __forceinline__ void convert_chunk(const float* sF, ushort* sB, int tid) {
#pragma unroll
  for (int j = 0; j < 4; ++j) {
    const int fi = j * 2048 + tid * 4;
    const float4 v = *reinterpret_cast<const float4*>(sF + fi);
    const int row = fi >> 7;
    const int col = fi & 127;
    const int c8 = col >> 3;
    ushort4 o;
    o.x = f2bf(v.x); o.y = f2bf(v.y); o.z = f2bf(v.z); o.w = f2bf(v.w);
    *reinterpret_cast<ushort4*>(sB + row * 128 + ((c8 ^ (row & 15)) << 3) + (col & 7)) = o;
  }
}

__device__ __forceinline__ void mfma_chunk(const ushort* __restrict__ buf,
    const ushort* __restrict__ Wp, int ktBase, f32x4 acc[4],
    int g, int lr, int colbase) {
#pragma unroll
  for (int j = 0; j < 4; ++j) {
    short8v b = ld8(Wp + (((ktBase + j) * 4 + g) * 128 + colbase) * 8);
    const int kcg = j * 4 + g;
#pragma unroll
    for (int rt = 0; rt < 4; ++rt) {
      const int row = rt * 16 + lr;
      short8v a = ld8(buf + row * 128 + ((kcg ^ (row & 15)) << 3));
      acc[rt] = MFMA16(a, b, acc[rt]);
    }
  }
}

__device__ __forceinline__ void epi_store(ushort* __restrict__ buf,
    const f32x4 acc[4], const float* __restrict__ bias, int colbase, int g) {
  const float bs = bias[colbase];
#pragma unroll
  for (int rt = 0; rt < 4; ++rt)
#pragma unroll
    for (int i = 0; i < 4; ++i) {
      const int rr = rt * 16 + g * 4 + i;
      buf[rr * 128 + ((((colbase >> 3) ^ (rr & 15)) << 3) | (colbase & 7))] =
          f2bf(gelu_f(acc[rt][i] + bs));
    }
}

// ---------------------------------------------------------------------------
// Message kernel: one node-pair per block, 512 threads (8 waves), 5000 blocks.
// h_E staged HBM->LDS asynchronously (global_load_lds, zero staging VGPRs),
// converted f32->bf16 in a short LDS pass, consumed by MFMA chunk-by-chunk.
// LDS 67KB -> 2 blocks/CU; inter-block desync keeps HBM fed at barriers.
// ---------------------------------------------------------------------------
__global__ __launch_bounds__(512, 4) void msg2(
    const float* __restrict__ hV, const float* __restrict__ hE,
    const float* __restrict__ mAtt, const ushort* __restrict__ wsu,
    const float* __restrict__ b1, const float* __restrict__ b2,
    const float* __restrict__ b3, const float* __restrict__ g1,
    const float* __restrict__ be1, float* __restrict__ hmidf,
    ushort* __restrict__ hmidb, int N) {
  const ushort* W1p = wsu;
  const ushort* W2p = wsu + 65536;
  const ushort* W3p = wsu + 81920;

  __shared__ float  sF[64 * 128];   // 32KB f32 staging (linear)
  __shared__ ushort sB0[64 * 128];  // 16KB bf16 tile (chunk0/chunk2, then H2)
  __shared__ ushort sB1[64 * 128];  // 16KB bf16 tile (chunk1, then H1)
  __shared__ ushort sHV[256];       // 2 nodes x 128 bf16
  __shared__ float  sDh[256];
  __shared__ float  sRed[16];

  const int tid = threadIdx.x;
  const int w = tid >> 6, lane = tid & 63;
  const int g = lane >> 4, lr = lane & 15;
  const int colbase = (w << 4) + lr;
  const int p = blockIdx.x;

  // ---- issue chunk0 async; stage hV -> sHV ----
  stage_issue(hE, sF, p, 0, tid, N);
  if (tid < 32) {
    const int nd = tid >> 4, c8 = tid & 15;
    const int n = 2 * p + nd;
    const int ncl = n < N ? n : 0;
    const float4* hp = reinterpret_cast<const float4*>(hV + (size_t)ncl * NH + c8 * 8);
    st8(sHV + nd * 128 + c8 * 8, pack8(hp[0], hp[1]));
  }
  __syncthreads();                       // drains c0

  convert_chunk(sF, sB0, tid);
  __syncthreads();

  stage_issue(hE, sF, p, 1, tid, N);     // c1 in flight under phase A

  f32x4 acc[4];
#pragma unroll
  for (int rt = 0; rt < 4; ++rt) acc[rt] = (f32x4){0.f, 0.f, 0.f, 0.f};

  // ===== layer-1 phase A: hV part (kt 0..3) + chunk0 =====
#pragma unroll
  for (int kt = 0; kt < 4; ++kt) {
    short8v bfr = ld8(W1p + ((kt * 4 + g) * 128 + colbase) * 8);
    short8v a0 = ld8(sHV + kt * 32 + g * 8);
    short8v a1 = ld8(sHV + 128 + kt * 32 + g * 8);
    acc[0] = MFMA16(a0, bfr, acc[0]);
    acc[1] = MFMA16(a0, bfr, acc[1]);
    acc[2] = MFMA16(a1, bfr, acc[2]);
    acc[3] = MFMA16(a1, bfr, acc[3]);
  }
  mfma_chunk(sB0, W1p, 4, acc, g, lr, colbase);
  __syncthreads();                       // drains c1

  convert_chunk(sF, sB1, tid);
  __syncthreads();

  stage_issue(hE, sF, p, 2, tid, N);     // c2 in flight under phase B

  // ===== layer-1 phase B: chunk1 =====
  mfma_chunk(sB1, W1p, 8, acc, g, lr, colbase);
  __syncthreads();                       // drains c2

  convert_chunk(sF, sB0, tid);           // sB0 free (chunk0 consumed)
  __syncthreads();

  // ===== layer-1 phase C: chunk2; epilogue H1 -> sB1 =====
  mfma_chunk(sB0, W1p, 12, acc, g, lr, colbase);
  epi_store(sB1, acc, b1, colbase, g);   // chunk1 reads finished 2 barriers ago
  __syncthreads();

  // ===== layer 2: sB1(H1) -> H2 -> sB0 =====
#pragma unroll
  for (int rt = 0; rt < 4; ++rt) acc[rt] = (f32x4){0.f, 0.f, 0.f, 0.f};
  mfma_chunk(sB1, W2p, 0, acc, g, lr, colbase);
  epi_store(sB0, acc, b2, colbase, g);
  __syncthreads();

  // ===== layer 3: sB0(H2) -> masked edge-sum =====
#pragma unroll
  for (int rt = 0; rt < 4; ++rt) acc[rt] = (f32x4){0.f, 0.f, 0.f, 0.f};
  mfma_chunk(sB0, W3p, 0, acc, g, lr, colbase);
  {
    const float bias = b3[colbase];
    float ns0 = 0.f, ns1 = 0.f;
#pragma unroll
    for (int rt = 0; rt < 4; ++rt) {
      const int nd = rt >> 1;
      float s = 0.f;
#pragma unroll
      for (int i = 0; i < 4; ++i) {
        const int e2 = (rt & 1) * 16 + g * 4 + i;
        const float m =
            (2 * p + nd < N) ? mAtt[(size_t)(2 * p + nd) * NK + e2] : 0.f;
        s += (acc[rt][i] + bias) * m;
      }
      s += __shfl_xor(s, 16, 64);
      s += __shfl_xor(s, 32, 64);
      if (rt < 2) ns0 += s; else ns1 += s;
    }
    if (g == 0) { sDh[colbase] = ns0; sDh[128 + colbase] = ns1; }
  }
  __syncthreads();

  // ===== LN1 + h_mid store =====
  float x_ln = 0.f;
  if (tid < 256) {
    const int nd = tid >> 7, i = tid & 127;
    const int gn = 2 * p + nd;
    if (gn < N)
      x_ln = hV[(size_t)gn * NH + i] + sDh[nd * NH + i] * (1.f / 30.f);
    float s = x_ln, qv = x_ln * x_ln;
#pragma unroll
    for (int d = 1; d < 64; d <<= 1) {
      s += __shfl_xor(s, d, 64);
      qv += __shfl_xor(qv, d, 64);
    }
    if (lane == 0) { sRed[w * 2] = s; sRed[w * 2 + 1] = qv; }
  }
  __syncthreads();
  if (tid < 256) {
    const int nd = tid >> 7, i = tid & 127;
    const int gn = 2 * p + nd;
    if (gn < N) {
      const int wb = nd * 2;
      const float s = sRed[wb * 2] + sRed[wb * 2 + 2];
      const float qv = sRed[wb * 2 + 1] + sRed[wb * 2 + 3];
      const float mean = s * (1.f / 128.f);
      const float var = qv * (1.f / 128.f) - mean * mean;
      const float y = (x_ln - mean) * rsqrtf(var + 1e-5f) * g1[i] + be1[i];
      hmidf[(size_t)gn * NH + i] = y;
      hmidb[(size_t)gn * NH + i] = f2bf(y);
    }
  }
}

// ---------------------------------------------------------------------------
// FFN kernel: 16 nodes / block (625 blocks), 256 threads (4 waves).
// ---------------------------------------------------------------------------
__global__ __launch_bounds__(256, 4) void ffn_kernel(
    const ushort* __restrict__ wsu, const float* __restrict__ binf,
    const float* __restrict__ boutf, const float* __restrict__ g2,
    const float* __restrict__ be2, const float* __restrict__ maskV,
    const float* __restrict__ hmidf, const ushort* __restrict__ hmidb,
    float* __restrict__ out, int N) {
  const ushort* Winp = wsu + 98304;
  const ushort* Woutp = wsu + 163840;

  __shared__ ushort sX[16 * 128];     // 4KB
  __shared__ ushort sHf[16 * 512];    // 16KB
  __shared__ float  sY[16 * 132];     // 8.25KB

  const int tid = threadIdx.x;
  const int w = tid >> 6, lane = tid & 63;
  const int g = lane >> 4, lr = lane & 15;
  const int n0 = blockIdx.x * 16;

  // stage h_mid (bf16) -> sX swizzled (256 chunks, one per thread)
  {
    const int rr = tid >> 4, c8 = tid & 15;
    const int n = n0 + rr;
    short8v v = {0, 0, 0, 0, 0, 0, 0, 0};
    if (n < N) v = ld8(hmidb + (size_t)n * NH + c8 * 8);
    st8(sX + rr * 128 + ((c8 ^ (rr & 15)) << 3), v);
  }
  __syncthreads();

  // -------- layer in: [16,128] @ Win -> gelu -> sHf [16,512] --------
#pragma unroll
  for (int ct8 = 0; ct8 < 8; ++ct8) {
    const int col = (w * 8 + ct8) * 16 + lr;
    f32x4 a0acc = (f32x4){0.f, 0.f, 0.f, 0.f};
#pragma unroll
    for (int kt = 0; kt < 4; ++kt) {
      short8v b = ld8(Winp + ((kt * 4 + g) * 512 + col) * 8);
      const int kcg = kt * 4 + g;
      const int r0 = lr;
      short8v a0 = ld8(sX + r0 * 128 + ((kcg ^ (r0 & 15)) << 3));
      a0acc = MFMA16(a0, b, a0acc);
    }
    const float bi = binf[col];
#pragma unroll
    for (int i = 0; i < 4; ++i) {
      const int rr = g * 4 + i;
      const float v0 = gelu_f(a0acc[i] + bi);
      sHf[rr * 512 + ((((col >> 3) ^ (rr & 15)) << 3) | (col & 7))] = f2bf(v0);
    }
  }
  __syncthreads();

  // -------- layer out: [16,512] @ Wout (wave w -> cols [w*32, w*32+32)) -----
  f32x4 o0 = (f32x4){0.f, 0.f, 0.f, 0.f}, o1 = o0;
#pragma unroll
  for (int kt = 0; kt < 16; ++kt) {
    const int kcg = kt * 4 + g;                 // [0,64)
    const int c0 = (2 * w) * 16 + lr, c1 = (2 * w + 1) * 16 + lr;
    short8v b0 = ld8(Woutp + (kcg * 128 + c0) * 8);
    short8v b1 = ld8(Woutp + (kcg * 128 + c1) * 8);
    const int r0 = lr;
    short8v a0 = ld8(sHf + r0 * 512 + ((kcg ^ (r0 & 15)) << 3));
    o0 = MFMA16(a0, b0, o0);
    o1 = MFMA16(a0, b1, o1);
  }
  // epilogue: + bias + residual -> sY
#pragma unroll
  for (int ct = 0; ct < 2; ++ct) {
    const int col = (2 * w + ct) * 16 + lr;
    const float bo = boutf[col];
    const f32x4 oo = ct ? o1 : o0;
#pragma unroll
    for (int i = 0; i < 4; ++i) {
      const int rr = g * 4 + i;
      const int n = n0 + rr;
      const float resid = (n < N) ? hmidf[(size_t)n * NH + col] : 0.f;
      sY[rr * 132 + col] = oo[i] + bo + resid;
    }
  }
  __syncthreads();

  // -------- LN2 + mask + store (16 threads per row, 8 cols each) --------
  {
    const int rr = tid >> 4, qq = tid & 15;
    const int n = n0 + rr;
    float vals[8];
    float s = 0.f, qs = 0.f;
    const float* yr = sY + rr * 132 + qq * 8;
#pragma unroll
    for (int j = 0; j < 8; ++j) { float x = yr[j]; vals[j] = x; s += x; qs += x * x; }
    s += __shfl_xor(s, 1, 64);  qs += __shfl_xor(qs, 1, 64);
    s += __shfl_xor(s, 2, 64);  qs += __shfl_xor(qs, 2, 64);
    s += __shfl_xor(s, 4, 64);  qs += __shfl_xor(qs, 4, 64);
    s += __shfl_xor(s, 8, 64);  qs += __shfl_xor(qs, 8, 64);
    const float mean = s * (1.f / 128.f);
    const float var = qs * (1.f / 128.f) - mean * mean;
    const float rs = rsqrtf(var + 1e-5f);
    if (n < N) {
      const float mv = maskV[n];
#pragma unroll
      for (int j = 0; j < 8; ++j) {
        const int col = qq * 8 + j;
        out[(size_t)n * NH + col] = ((vals[j] - mean) * rs * g2[col] + be2[col]) * mv;
      }
    }
  }
}

extern "C" void kernel_launch(void* const* d_in, const int* in_sizes, int n_in,
                              void* d_out, int out_size, void* d_ws, size_t ws_size,
                              hipStream_t stream) {
  const float* hV   = (const float*)d_in[0];
  const float* hE   = (const float*)d_in[1];
  const float* mV   = (const float*)d_in[2];
  const float* mAtt = (const float*)d_in[3];
  const float* W1   = (const float*)d_in[4];
  const float* b1   = (const float*)d_in[5];
  const float* W2   = (const float*)d_in[6];
  const float* b2   = (const float*)d_in[7];
  const float* W3   = (const float*)d_in[8];
  const float* b3   = (const float*)d_in[9];
  const float* g1   = (const float*)d_in[10];
  const float* be1  = (const float*)d_in[11];
  const float* Win  = (const float*)d_in[12];
  const float* binf = (const float*)d_in[13];
  const float* Wout = (const float*)d_in[14];
  const float* bout = (const float*)d_in[15];
  const float* g2   = (const float*)d_in[16];
  const float* be2  = (const float*)d_in[17];

  const int N = in_sizes[0] / NH;

  ushort* wsu = (ushort*)d_ws;                         // packed weights: 448 KB
  float*  hmidf = (float*)((char*)d_ws + 458752);      // N*128 f32
  ushort* hmidb = (ushort*)((char*)d_ws + 458752 + (size_t)N * NH * 4);  // N*128 bf16

  pack_w<<<896, 256, 0, stream>>>(W1, W2, W3, Win, Wout, wsu);

  const int pairs = (N + 1) / 2;
  msg2<<<pairs, 512, 0, stream>>>(hV, hE, mAtt, wsu, b1, b2, b3, g1, be1,
                                  hmidf, hmidb, N);
  ffn_kernel<<<(N + 15) / 16, 256, 0, stream>>>(wsu, binf, bout, g2, be2, mV,
                                                hmidf, hmidb, (float*)d_out, N);
  (void)n_in; (void)out_size; (void)ws_size;
}

// Round 8
// 167.994 us; speedup vs baseline: 2.6356x; 1.0952x over previous
//
#include <hip/hip_runtime.h>
#include <hip/hip_bf16.h>

#define NH 128   // hidden
#define NC 384   // edge feature dim
#define NK 32    // neighbors

typedef __attribute__((ext_vector_type(8))) short short8v;   // 8 bf16
typedef __attribute__((ext_vector_type(4))) float f32x4;

#define MFMA16(a, b, c) __builtin_amdgcn_mfma_f32_16x16x32_bf16((a), (b), (c), 0, 0, 0)

__device__ __forceinline__ ushort f2bf(float x) {
  __hip_bfloat16 h = __float2bfloat16(x);   // RNE; packs to v_cvt_pk_bf16_f32
  ushort u;
  __builtin_memcpy(&u, &h, 2);
  return u;
}

__device__ __forceinline__ short8v ld8(const ushort* p) {
  return *reinterpret_cast<const short8v*>(p);
}
__device__ __forceinline__ void st8(ushort* p, short8v v) {
  *reinterpret_cast<short8v*>(p) = v;
}

__device__ __forceinline__ short8v pack8(float4 a, float4 b) {
  short8v v;
  v[0] = (short)f2bf(a.x); v[1] = (short)f2bf(a.y);
  v[2] = (short)f2bf(a.z); v[3] = (short)f2bf(a.w);
  v[4] = (short)f2bf(b.x); v[5] = (short)f2bf(b.y);
  v[6] = (short)f2bf(b.z); v[7] = (short)f2bf(b.w);
  return v;
}

// gelu(x) = x * sigmoid(x*(1.5958 + 0.07136 x^2)); |err| vs erf-GELU < 1e-3
__device__ __forceinline__ float gelu_f(float x) {
  float x2 = x * x;
  float m = __builtin_fmaf(0.07135481283f, x2, 1.595769122f);
  float e = __expf(-x * m);
  return x * __builtin_amdgcn_rcpf(1.0f + e);
}

// barrier that does NOT drain vmcnt: LDS writes visible, global loads stay in
// flight. sched_barrier(0) pins codegen around the inline-asm waitcnt (rule 18).
__device__ __forceinline__ void lds_barrier() {
  asm volatile("s_waitcnt lgkmcnt(0)" ::: "memory");
  __builtin_amdgcn_sched_barrier(0);
  __builtin_amdgcn_s_barrier();
}

// ---------------------------------------------------------------------------
// Weight packing: src row-major [k][col] f32 -> bf16 [k/8][col][k%8]
// ushort offsets: W1p 0 (64Ki), W2p 65536 (16Ki), W3p 81920 (16Ki),
// Winp 98304 (64Ki), Woutp 163840 (64Ki). Total 448 KB.
// ---------------------------------------------------------------------------
__global__ __launch_bounds__(256) void pack_w(
    const float* __restrict__ W1, const float* __restrict__ W2,
    const float* __restrict__ W3, const float* __restrict__ Win,
    const float* __restrict__ Wout, ushort* __restrict__ ws) {
  int id = blockIdx.x * 256 + threadIdx.x;
  if (id < 65536) {                       // W1: K=512, ncol=128
    int t = id, k = t >> 7, c = t & 127;
    ws[(((k >> 3) << 7) + c) * 8 + (k & 7)] = f2bf(W1[t]);
  } else if (id < 81920) {                // W2
    int t = id - 65536, k = t >> 7, c = t & 127;
    ws[65536 + (((k >> 3) << 7) + c) * 8 + (k & 7)] = f2bf(W2[t]);
  } else if (id < 98304) {                // W3
    int t = id - 81920, k = t >> 7, c = t & 127;
    ws[81920 + (((k >> 3) << 7) + c) * 8 + (k & 7)] = f2bf(W3[t]);
  } else if (id < 163840) {               // Win: K=128, ncol=512
    int t = id - 98304, k = t >> 9, c = t & 511;
    ws[98304 + (((k >> 3) << 9) + c) * 8 + (k & 7)] = f2bf(Win[t]);
  } else {                                // Wout: K=512, ncol=128
    int t = id - 163840, k = t >> 7, c = t & 127;
    ws[163840 + (((k >> 3) << 7) + c) * 8 + (k & 7)] = f2bf(Wout[t]);
  }
}

// ---------- msg3 helpers ----------

// issue global loads of 64-col chunk c of pair p: 8 f32/thread (2 dwordx4)
__device__ __forceinline__ void issue_chunk(const float* __restrict__ hE,
    int p, int c, int tid, int N, float4& a, float4& b) {
  const int r = tid >> 3;              // row 0..63 (node*32 + edge)
  const int cb = (tid & 7) * 8;        // col base within chunk
  const int node = r >> 5, e = r & 31;
  int n = 2 * p + node;
  if (n >= N) n = 0;
  const float* g = hE + ((size_t)n * NK + e) * NC + c * 64 + cb;
  const float4* gp = reinterpret_cast<const float4*>(g);
  a = gp[0];
  b = gp[1];
}

// convert staged regs -> 64x64 bf16 tile (granule XOR-swizzled)
__device__ __forceinline__ void convert_regs(ushort* __restrict__ sC, int tid,
    float4 a, float4 b, bool zz) {
  const int r = tid >> 3, cg = tid & 7;
  short8v v = zz ? (short8v){0, 0, 0, 0, 0, 0, 0, 0} : pack8(a, b);
  st8(sC + r * 64 + ((cg ^ (r & 7)) << 3), v);
}

// MFMA over one 64-col chunk j (k global [128+j*64, 128+(j+1)*64))
__device__ __forceinline__ void mfma_chunk64(const ushort* __restrict__ sC,
    const ushort* __restrict__ W1p, int j, f32x4 acc[4],
    int g, int lr, int outcol) {
#pragma unroll
  for (int jj = 0; jj < 2; ++jj) {
    short8v bfr = ld8(W1p + (((16 + j * 8 + jj * 4 + g) * 128) + outcol) * 8);
    const int akg = jj * 4 + g;
#pragma unroll
    for (int rt = 0; rt < 4; ++rt) {
      const int row = rt * 16 + lr;
      short8v af = ld8(sC + row * 64 + ((akg ^ (row & 7)) << 3));
      acc[rt] = MFMA16(af, bfr, acc[rt]);
    }
  }
}

// 128-wide helpers for H1/H2 (granule space 16, row&15 swizzle)
__device__ __forceinline__ void mfma_chunk(const ushort* __restrict__ buf,
    const ushort* __restrict__ Wp, int ktBase, f32x4 acc[4],
    int g, int lr, int outcol) {
#pragma unroll
  for (int j = 0; j < 4; ++j) {
    short8v bfr = ld8(Wp + (((ktBase + j) * 4 + g) * 128 + outcol) * 8);
    const int kcg = j * 4 + g;
#pragma unroll
    for (int rt = 0; rt < 4; ++rt) {
      const int row = rt * 16 + lr;
      short8v af = ld8(buf + row * 128 + ((kcg ^ (row & 15)) << 3));
      acc[rt] = MFMA16(af, bfr, acc[rt]);
    }
  }
}

__device__ __forceinline__ void epi_store(ushort* __restrict__ buf,
    const f32x4 acc[4], const float* __restrict__ bias, int outcol, int g) {
  const float bs = bias[outcol];
#pragma unroll
  for (int rt = 0; rt < 4; ++rt)
#pragma unroll
    for (int i = 0; i < 4; ++i) {
      const int rr = rt * 16 + g * 4 + i;
      buf[rr * 128 + ((((outcol >> 3) ^ (rr & 15)) << 3) | (outcol & 7))] =
          f2bf(gelu_f(acc[rt][i] + bs));
    }
}

// ---------------------------------------------------------------------------
// Message kernel v3: one node-pair per block, 512 threads, 5000 blocks.
// h_E in 6x(64-col) chunks, reg-staged (8 f32/thread live, 2 banks), bf16
// tiles double-buffered in 2x8KB LDS. Custom lgkm-only barriers keep the
// next-next chunk's global loads in flight across every sync point.
// LDS ~34KB. sC region (16KB) is reused as H1 after layer 1.
// ---------------------------------------------------------------------------
__global__ __launch_bounds__(512, 4) void msg3(
    const float* __restrict__ hV, const float* __restrict__ hE,
    const float* __restrict__ mAtt, const ushort* __restrict__ wsu,
    const float* __restrict__ b1, const float* __restrict__ b2,
    const float* __restrict__ b3, const float* __restrict__ g1,
    const float* __restrict__ be1, float* __restrict__ hmidf,
    ushort* __restrict__ hmidb, int N) {
  const ushort* W1p = wsu;
  const ushort* W2p = wsu + 65536;
  const ushort* W3p = wsu + 81920;

  __shared__ ushort sC[2][4096];    // 2 x 8KB bf16 chunk tiles; reused as H1
  __shared__ ushort sH2[8192];      // 16KB H2
  __shared__ ushort sHV[256];       // 2 nodes x 128 bf16
  __shared__ float  sDh[256];
  __shared__ float  sRed[16];

  const int tid = threadIdx.x;
  const int w = tid >> 6, lane = tid & 63;
  const int g = lane >> 4, lr = lane & 15;
  const int outcol = (w << 4) + lr;
  const int p = blockIdx.x;
  const bool zz = (2 * p + ((tid >> 3) >> 5)) >= N;   // staging-row validity

  float4 eA, eB, oA, oB;   // two 8-f32 staging banks (even/odd chunks)

  // ---- prologue: get memory going immediately ----
  issue_chunk(hE, p, 0, tid, N, eA, eB);
  issue_chunk(hE, p, 1, tid, N, oA, oB);
  if (tid < 32) {
    const int nd = tid >> 4, c8 = tid & 15;
    const int n = 2 * p + nd;
    const int ncl = n < N ? n : 0;
    const float4* hp = reinterpret_cast<const float4*>(hV + (size_t)ncl * NH + c8 * 8);
    st8(sHV + nd * 128 + c8 * 8, pack8(hp[0], hp[1]));
  }
  convert_regs(sC[0], tid, eA, eB, zz);   // c0 (compiler waits on eA/eB)
  lds_barrier();

  f32x4 acc[4];
#pragma unroll
  for (int rt = 0; rt < 4; ++rt) acc[rt] = (f32x4){0.f, 0.f, 0.f, 0.f};

  // ===== layer-1 hV part (k 0..127, granules 0..15) =====
#pragma unroll
  for (int kt = 0; kt < 4; ++kt) {
    short8v bfr = ld8(W1p + ((kt * 4 + g) * 128 + outcol) * 8);
    short8v a0 = ld8(sHV + kt * 32 + g * 8);
    short8v a1 = ld8(sHV + 128 + kt * 32 + g * 8);
    acc[0] = MFMA16(a0, bfr, acc[0]);
    acc[1] = MFMA16(a0, bfr, acc[1]);
    acc[2] = MFMA16(a1, bfr, acc[2]);
    acc[3] = MFMA16(a1, bfr, acc[3]);
  }

  // ===== layer-1 h_E chunks, software-pipelined =====
  // j=0: consume c0; convert c1; issue c2
  issue_chunk(hE, p, 2, tid, N, eA, eB);
  mfma_chunk64(sC[0], W1p, 0, acc, g, lr, outcol);
  convert_regs(sC[1], tid, oA, oB, zz);
  lds_barrier();
  // j=1: consume c1; convert c2; issue c3
  issue_chunk(hE, p, 3, tid, N, oA, oB);
  mfma_chunk64(sC[1], W1p, 1, acc, g, lr, outcol);
  convert_regs(sC[0], tid, eA, eB, zz);
  lds_barrier();
  // j=2: consume c2; convert c3; issue c4
  issue_chunk(hE, p, 4, tid, N, eA, eB);
  mfma_chunk64(sC[0], W1p, 2, acc, g, lr, outcol);
  convert_regs(sC[1], tid, oA, oB, zz);
  lds_barrier();
  // j=3: consume c3; convert c4; issue c5
  issue_chunk(hE, p, 5, tid, N, oA, oB);
  mfma_chunk64(sC[1], W1p, 3, acc, g, lr, outcol);
  convert_regs(sC[0], tid, eA, eB, zz);
  lds_barrier();
  // j=4: consume c4; convert c5
  mfma_chunk64(sC[0], W1p, 4, acc, g, lr, outcol);
  convert_regs(sC[1], tid, oA, oB, zz);
  lds_barrier();
  // j=5: consume c5
  mfma_chunk64(sC[1], W1p, 5, acc, g, lr, outcol);
  __syncthreads();

  // ===== layer-1 epilogue: H1 -> sC region (as [64][128]) =====
  ushort* sH1 = &sC[0][0];
  epi_store(sH1, acc, b1, outcol, g);
  __syncthreads();

  // ===== layer 2: H1 -> H2 =====
#pragma unroll
  for (int rt = 0; rt < 4; ++rt) acc[rt] = (f32x4){0.f, 0.f, 0.f, 0.f};
  mfma_chunk(sH1, W2p, 0, acc, g, lr, outcol);
  epi_store(sH2, acc, b2, outcol, g);
  __syncthreads();

  // ===== layer 3: H2 -> masked edge-sum =====
#pragma unroll
  for (int rt = 0; rt < 4; ++rt) acc[rt] = (f32x4){0.f, 0.f, 0.f, 0.f};
  mfma_chunk(sH2, W3p, 0, acc, g, lr, outcol);
  {
    const float bias = b3[outcol];
    float ns0 = 0.f, ns1 = 0.f;
#pragma unroll
    for (int rt = 0; rt < 4; ++rt) {
      const int nd = rt >> 1;
      float s = 0.f;
#pragma unroll
      for (int i = 0; i < 4; ++i) {
        const int e2 = (rt & 1) * 16 + g * 4 + i;
        const float m =
            (2 * p + nd < N) ? mAtt[(size_t)(2 * p + nd) * NK + e2] : 0.f;
        s += (acc[rt][i] + bias) * m;
      }
      s += __shfl_xor(s, 16, 64);
      s += __shfl_xor(s, 32, 64);
      if (rt < 2) ns0 += s; else ns1 += s;
    }
    if (g == 0) { sDh[outcol] = ns0; sDh[128 + outcol] = ns1; }
  }
  __syncthreads();

  // ===== LN1 + h_mid store =====
  float x_ln = 0.f;
  if (tid < 256) {
    const int nd = tid >> 7, i = tid & 127;
    const int gn = 2 * p + nd;
    if (gn < N)
      x_ln = hV[(size_t)gn * NH + i] + sDh[nd * NH + i] * (1.f / 30.f);
    float s = x_ln, qv = x_ln * x_ln;
#pragma unroll
    for (int d = 1; d < 64; d <<= 1) {
      s += __shfl_xor(s, d, 64);
      qv += __shfl_xor(qv, d, 64);
    }
    if (lane == 0) { sRed[w * 2] = s; sRed[w * 2 + 1] = qv; }
  }
  __syncthreads();
  if (tid < 256) {
    const int nd = tid >> 7, i = tid & 127;
    const int gn = 2 * p + nd;
    if (gn < N) {
      const int wb = nd * 2;
      const float s = sRed[wb * 2] + sRed[wb * 2 + 2];
      const float qv = sRed[wb * 2 + 1] + sRed[wb * 2 + 3];
      const float mean = s * (1.f / 128.f);
      const float var = qv * (1.f / 128.f) - mean * mean;
      const float y = (x_ln - mean) * rsqrtf(var + 1e-5f) * g1[i] + be1[i];
      hmidf[(size_t)gn * NH + i] = y;
      hmidb[(size_t)gn * NH + i] = f2bf(y);
    }
  }
}

// ---------------------------------------------------------------------------
// FFN kernel: 16 nodes / block (625 blocks), 256 threads (4 waves).
// ---------------------------------------------------------------------------
__global__ __launch_bounds__(256, 4) void ffn_kernel(
    const ushort* __restrict__ wsu, const float* __restrict__ binf,
    const float* __restrict__ boutf, const float* __restrict__ g2,
    const float* __restrict__ be2, const float* __restrict__ maskV,
    const float* __restrict__ hmidf, const ushort* __restrict__ hmidb,
    float* __restrict__ out, int N) {
  const ushort* Winp = wsu + 98304;
  const ushort* Woutp = wsu + 163840;

  __shared__ ushort sX[16 * 128];     // 4KB
  __shared__ ushort sHf[16 * 512];    // 16KB
  __shared__ float  sY[16 * 132];     // 8.25KB

  const int tid = threadIdx.x;
  const int w = tid >> 6, lane = tid & 63;
  const int g = lane >> 4, lr = lane & 15;
  const int n0 = blockIdx.x * 16;

  // stage h_mid (bf16) -> sX swizzled (256 chunks, one per thread)
  {
    const int rr = tid >> 4, c8 = tid & 15;
    const int n = n0 + rr;
    short8v v = {0, 0, 0, 0, 0, 0, 0, 0};
    if (n < N) v = ld8(hmidb + (size_t)n * NH + c8 * 8);
    st8(sX + rr * 128 + ((c8 ^ (rr & 15)) << 3), v);
  }
  __syncthreads();

  // -------- layer in: [16,128] @ Win -> gelu -> sHf [16,512] --------
#pragma unroll
  for (int ct8 = 0; ct8 < 8; ++ct8) {
    const int col = (w * 8 + ct8) * 16 + lr;
    f32x4 a0acc = (f32x4){0.f, 0.f, 0.f, 0.f};
#pragma unroll
    for (int kt = 0; kt < 4; ++kt) {
      short8v b = ld8(Winp + ((kt * 4 + g) * 512 + col) * 8);
      const int kcg = kt * 4 + g;
      const int r0 = lr;
      short8v a0 = ld8(sX + r0 * 128 + ((kcg ^ (r0 & 15)) << 3));
      a0acc = MFMA16(a0, b, a0acc);
    }
    const float bi = binf[col];
#pragma unroll
    for (int i = 0; i < 4; ++i) {
      const int rr = g * 4 + i;
      const float v0 = gelu_f(a0acc[i] + bi);
      sHf[rr * 512 + ((((col >> 3) ^ (rr & 15)) << 3) | (col & 7))] = f2bf(v0);
    }
  }
  __syncthreads();

  // -------- layer out: [16,512] @ Wout (wave w -> cols [w*32, w*32+32)) -----
  f32x4 o0 = (f32x4){0.f, 0.f, 0.f, 0.f}, o1 = o0;
#pragma unroll
  for (int kt = 0; kt < 16; ++kt) {
    const int kcg = kt * 4 + g;                 // [0,64)
    const int c0 = (2 * w) * 16 + lr, c1 = (2 * w + 1) * 16 + lr;
    short8v b0 = ld8(Woutp + (kcg * 128 + c0) * 8);
    short8v b1 = ld8(Woutp + (kcg * 128 + c1) * 8);
    const int r0 = lr;
    short8v a0 = ld8(sHf + r0 * 512 + ((kcg ^ (r0 & 15)) << 3));
    o0 = MFMA16(a0, b0, o0);
    o1 = MFMA16(a0, b1, o1);
  }
  // epilogue: + bias + residual -> sY
#pragma unroll
  for (int ct = 0; ct < 2; ++ct) {
    const int col = (2 * w + ct) * 16 + lr;
    const float bo = boutf[col];
    const f32x4 oo = ct ? o1 : o0;
#pragma unroll
    for (int i = 0; i < 4; ++i) {
      const int rr = g * 4 + i;
      const int n = n0 + rr;
      const float resid = (n < N) ? hmidf[(size_t)n * NH + col] : 0.f;
      sY[rr * 132 + col] = oo[i] + bo + resid;
    }
  }
  __syncthreads();

  // -------- LN2 + mask + store (16 threads per row, 8 cols each) --------
  {
    const int rr = tid >> 4, qq = tid & 15;
    const int n = n0 + rr;
    float vals[8];
    float s = 0.f, qs = 0.f;
    const float* yr = sY + rr * 132 + qq * 8;
#pragma unroll
    for (int j = 0; j < 8; ++j) { float x = yr[j]; vals[j] = x; s += x; qs += x * x; }
    s += __shfl_xor(s, 1, 64);  qs += __shfl_xor(qs, 1, 64);
    s += __shfl_xor(s, 2, 64);  qs += __shfl_xor(qs, 2, 64);
    s += __shfl_xor(s, 4, 64);  qs += __shfl_xor(qs, 4, 64);
    s += __shfl_xor(s, 8, 64);  qs += __shfl_xor(qs, 8, 64);
    const float mean = s * (1.f / 128.f);
    const float var = qs * (1.f / 128.f) - mean * mean;
    const float rs = rsqrtf(var + 1e-5f);
    if (n < N) {
      const float mv = maskV[n];
#pragma unroll
      for (int j = 0; j < 8; ++j) {
        const int col = qq * 8 + j;
        out[(size_t)n * NH + col] = ((vals[j] - mean) * rs * g2[col] + be2[col]) * mv;
      }
    }
  }
}

extern "C" void kernel_launch(void* const* d_in, const int* in_sizes, int n_in,
                              void* d_out, int out_size, void* d_ws, size_t ws_size,
                              hipStream_t stream) {
  const float* hV   = (const float*)d_in[0];
  const float* hE   = (const float*)d_in[1];
  const float* mV   = (const float*)d_in[2];
  const float* mAtt = (const float*)d_in[3];
  const float* W1   = (const float*)d_in[4];
  const float* b1   = (const float*)d_in[5];
  const float* W2   = (const float*)d_in[6];
  const float* b2   = (const float*)d_in[7];
  const float* W3   = (const float*)d_in[8];
  const float* b3   = (const float*)d_in[9];
  const float* g1   = (const float*)d_in[10];
  const float* be1  = (const float*)d_in[11];
  const float* Win  = (const float*)d_in[12];
  const float* binf = (const float*)d_in[13];
  const float* Wout = (const float*)d_in[14];
  const float* bout = (const float*)d_in[15];
  const float* g2   = (const float*)d_in[16];
  const float* be2  = (const float*)d_in[17];

  const int N = in_sizes[0] / NH;

  ushort* wsu = (ushort*)d_ws;                         // packed weights: 448 KB
  float*  hmidf = (float*)((char*)d_ws + 458752);      // N*128 f32
  ushort* hmidb = (ushort*)((char*)d_ws + 458752 + (size_t)N * NH * 4);  // N*128 bf16

  pack_w<<<896, 256, 0, stream>>>(W1, W2, W3, Win, Wout, wsu);

  const int pairs = (N + 1) / 2;
  msg3<<<pairs, 512, 0, stream>>>(hV, hE, mAtt, wsu, b1, b2, b3, g1, be1,
                                  hmidf, hmidb, N);
  ffn_kernel<<<(N + 15) / 16, 256, 0, stream>>>(wsu, binf, bout, g2, be2, mV,
                                                hmidf, hmidb, (float*)d_out, N);
  (void)n_in; (void)out_size; (void)ws_size;
}